// Round 8
// baseline (2871.669 us; speedup 1.0000x reference)
//
#include <hip/hip_runtime.h>
#include <hip/hip_bf16.h>
#include <math.h>

namespace {
constexpr int Bc = 64, Nc = 2048, Dc = 256, Hc = 8, DHc = 32, Sc = 10;
constexpr float kNeg = -1000000000.0f;
constexpr float kClip = 10.0f;
constexpr float kScale = 0.17677669529663687f;   // 1/sqrt(32)
constexpr float kScale2 = 0.0625f;               // 1/sqrt(256)
}

// ---- h_mean partials: 2048 blocks, 64-row chunks ----
__global__ __launch_bounds__(256) void k_hmean_part(const float* __restrict__ enc,
                                                    float* __restrict__ hpart) {
  int b = blockIdx.x >> 5, c = blockIdx.x & 31, d = threadIdx.x;
  const float* p = enc + ((size_t)b * Nc + c * 64) * Dc + d;
  float s = 0.f;
  #pragma unroll 8
  for (int n = 0; n < 64; ++n) s += p[(size_t)n * Dc];
  hpart[(size_t)blockIdx.x * Dc + d] = s;
}

// ---- qgc (folds hmean reduction): q, g, c ----
__global__ __launch_bounds__(256) void k_qgc(const float* __restrict__ hpart,
                                             const float* __restrict__ w_in,
                                             const float* __restrict__ b_in,
                                             float* __restrict__ g, float* __restrict__ c) {
  int b = blockIdx.x, t = threadIdx.x;
  __shared__ float hm[Dc];
  __shared__ float qsh[Dc];
  {
    float s = 0.f;
    for (int cc = 0; cc < 32; ++cc) s += hpart[(size_t)(b * 32 + cc) * Dc + t];
    hm[t] = s * (1.0f / Nc);
  }
  __syncthreads();
  {
    const float* row = w_in + (size_t)t * Dc;  // Wq row t
    float acc = b_in[t];
    for (int d = 0; d < Dc; ++d) acc += row[d] * hm[d];
    qsh[t] = acc;
  }
  __syncthreads();
  for (int h = 0; h < Hc; ++h) {
    float acc = 0.f;
    const float* wk = w_in + (size_t)(Dc + h * DHc) * Dc + t;  // Wk rows, col t
    const float* qh = qsh + h * DHc;
    #pragma unroll 8
    for (int i = 0; i < DHc; ++i) acc += qh[i] * wk[(size_t)i * Dc];
    g[((size_t)b * Hc + h) * Dc + t] = acc;
  }
  if (t < Hc) {
    float acc = 0.f;
    for (int i = 0; i < DHc; ++i) acc += qsh[t * DHc + i] * b_in[Dc + t * DHc + i];
    c[b * Hc + t] = acc;
  }
}

// ---- setup: M1 = sha_wq @ out_w ; m1b = sha_wq @ out_b ----
__global__ __launch_bounds__(256) void k_A1(const float* __restrict__ swq,
                                            const float* __restrict__ ow,
                                            const float* __restrict__ ob,
                                            float* __restrict__ M1, float* __restrict__ m1b) {
  int i = blockIdx.x, e = threadIdx.x;
  __shared__ float row[Dc];
  __shared__ float red[256];
  row[e] = swq[(size_t)i * Dc + e];
  __syncthreads();
  float acc = 0.f;
  #pragma unroll 4
  for (int k = 0; k < Dc; ++k) acc += row[k] * ow[(size_t)k * Dc + e];
  M1[(size_t)i * Dc + e] = acc;
  red[e] = row[e] * ob[e];
  __syncthreads();
  for (int off = 128; off >= 1; off >>= 1) {
    if (e < off) red[e] += red[e + off];
    __syncthreads();
  }
  if (e == 0) m1b[i] = red[0];
}

// ---- setup: A = sha_wk^T @ M1 ; cvec = A@bv + sha_wk^T@m1b ----
__global__ __launch_bounds__(256) void k_A2(const float* __restrict__ swk,
                                            const float* __restrict__ M1,
                                            const float* __restrict__ m1b,
                                            const float* __restrict__ b_in,
                                            float* __restrict__ Aout, float* __restrict__ cvec) {
  int d = blockIdx.x, e = threadIdx.x;
  __shared__ float col[Dc];
  __shared__ float red[256];
  col[e] = swk[(size_t)e * Dc + d];
  __syncthreads();
  float acc = 0.f;
  #pragma unroll 4
  for (int k = 0; k < Dc; ++k) acc += col[k] * M1[(size_t)k * Dc + e];
  Aout[(size_t)d * Dc + e] = acc;
  red[e] = acc * b_in[2 * Dc + e] + col[e] * m1b[e];
  __syncthreads();
  for (int off = 128; off >= 1; off >>= 1) {
    if (e < off) red[e] += red[e + off];
    __syncthreads();
  }
  if (e == 0) cvec[d] = red[0];
}

// ---- setup: BT[(h*256+e)*256+d] = sum_i A[d][h*32+i] * Wv[h*32+i][e] ----
__global__ __launch_bounds__(256) void k_A3(const float* __restrict__ Aout,
                                            const float* __restrict__ w_in,
                                            float* __restrict__ BT) {
  int h = blockIdx.x >> 3, et = blockIdx.x & 7, d = threadIdx.x;
  float arow[DHc];
  #pragma unroll
  for (int i = 0; i < DHc; ++i) arow[i] = Aout[(size_t)d * Dc + h * DHc + i];
  __shared__ float wv[DHc][DHc];
  for (int k = threadIdx.x; k < DHc * DHc; k += 256) {
    int i = k >> 5, j = k & 31;
    wv[i][j] = w_in[(size_t)(2 * Dc + h * DHc + i) * Dc + et * DHc + j];
  }
  __syncthreads();
  for (int j = 0; j < DHc; ++j) {
    float acc = 0.f;
    #pragma unroll
    for (int i = 0; i < DHc; ++i) acc += arow[i] * wv[i][j];
    BT[((size_t)h * Dc + et * DHc + j) * Dc + d] = acc;
  }
}

// ---- scores: 2 threads per row, 1024 blocks ----
__global__ __launch_bounds__(256) void k_scores(const float* __restrict__ enc,
                                                const float* __restrict__ g,
                                                const float* __restrict__ c,
                                                float* __restrict__ s) {
  int b = blockIdx.x >> 4, nt = blockIdx.x & 15, t = threadIdx.x;
  __shared__ __align__(16) float gsm[Hc * Dc];
  __shared__ float csm[Hc];
  for (int k = t; k < Hc * Dc; k += 256) gsm[k] = g[(size_t)b * Hc * Dc + k];
  if (t < Hc) csm[t] = c[b * Hc + t];
  __syncthreads();
  int row = t >> 1, half = t & 1;
  int n = nt * 128 + row;
  const float4* rowp = reinterpret_cast<const float4*>(enc + ((size_t)b * Nc + n) * Dc);
  float acc[Hc] = {};
  #pragma unroll 8
  for (int i = 0; i < 32; ++i) {
    int d4 = i * 2 + half;
    const float4 e = rowp[d4];
    #pragma unroll
    for (int h = 0; h < Hc; ++h) {
      const float4 g4 = *reinterpret_cast<const float4*>(gsm + h * Dc + d4 * 4);
      acc[h] += e.x * g4.x + e.y * g4.y + e.z * g4.z + e.w * g4.w;
    }
  }
  #pragma unroll
  for (int h = 0; h < Hc; ++h) acc[h] += __shfl_xor(acc[h], 1);
  if (half == 0) {
    #pragma unroll
    for (int h = 0; h < Hc; ++h)
      s[((size_t)b * Hc + h) * Nc + n] = kScale * (acc[h] + csm[h]);
  }
}

// ---- rowmax per (b,h) ----
__global__ __launch_bounds__(256) void k_rowmax(const float* __restrict__ s,
                                                float* __restrict__ mrow) {
  int bh = blockIdx.x, t = threadIdx.x;
  __shared__ float red[256];
  float m = -3.0e38f;
  #pragma unroll
  for (int q = 0; q < 8; ++q) m = fmaxf(m, s[(size_t)bh * Nc + q * 256 + t]);
  red[t] = m;
  __syncthreads();
  for (int off = 128; off >= 1; off >>= 1) {
    if (t < off) red[t] = fmaxf(red[t], red[t + off]);
    __syncthreads();
  }
  if (t == 0) mrow[bh] = red[0];
}

// ---- S0 partials (+exp fold: w = exp(s-m)) ----
__global__ __launch_bounds__(256) void k_S0part(const float* __restrict__ enc,
                                                const float* __restrict__ s,
                                                const float* __restrict__ mrow,
                                                float* __restrict__ w,
                                                float* __restrict__ Spart) {
  int b = blockIdx.x >> 3, cid = blockIdx.x & 7, t = threadIdx.x;
  __shared__ float wsm[Hc * 256];
  #pragma unroll
  for (int h = 0; h < Hc; ++h) {
    float m = mrow[b * Hc + h];
    float e = expf(s[((size_t)b * Hc + h) * Nc + cid * 256 + t] - m);
    wsm[h * 256 + t] = e;
    w[((size_t)b * Hc + h) * Nc + cid * 256 + t] = e;
  }
  __syncthreads();
  float acc[Hc] = {};
  const float* ep = enc + ((size_t)b * Nc + cid * 256) * Dc + t;
  for (int ni = 0; ni < 256; ++ni) {
    float ev = ep[(size_t)ni * Dc];
    #pragma unroll
    for (int h = 0; h < Hc; ++h) acc[h] += wsm[h * 256 + ni] * ev;
  }
  #pragma unroll
  for (int h = 0; h < Hc; ++h)
    Spart[(((size_t)b * 8 + cid) * Hc + h) * Dc + t] = acc[h];
}

// ---- S0 reduce + W0 = sum_n w ; init sync flags ----
__global__ __launch_bounds__(256) void k_S0red(const float* __restrict__ Spart,
                                               const float* __restrict__ w,
                                               float* __restrict__ Sacc,
                                               float* __restrict__ W0,
                                               unsigned* __restrict__ flag) {
  int b = blockIdx.x >> 3, h = blockIdx.x & 7, t = threadIdx.x;
  __shared__ float red[256];
  if (t == 0 && h == 0)
    __hip_atomic_store(&flag[b], 0u, __ATOMIC_RELAXED, __HIP_MEMORY_SCOPE_AGENT);
  float acc = 0.f;
  for (int cid = 0; cid < 8; ++cid)
    acc += Spart[(((size_t)b * 8 + cid) * Hc + h) * Dc + t];
  Sacc[((size_t)b * Hc + h) * Dc + t] = acc;
  float ws = 0.f;
  #pragma unroll
  for (int q = 0; q < 8; ++q) ws += w[((size_t)b * Hc + h) * Nc + q * 256 + t];
  red[t] = ws;
  __syncthreads();
  for (int off = 128; off >= 1; off >>= 1) {
    if (t < off) red[t] += red[t + off];
    __syncthreads();
  }
  if (t == 0) W0[b * Hc + h] = red[0];
}

// ---- shared select core: masked log-softmax + argmax + entropy ----
__device__ __forceinline__ void select_core(const float* __restrict__ ub,
                                            const int* histsh, int nhist, int t,
                                            float* red, int* redi,
                                            int& gidx_out, float& lse_out, float& ent_out) {
  float uval[8];
  float lmax = -3.0e38f;
  int lidx = 0;
  #pragma unroll
  for (int q = 0; q < 8; ++q) {
    int n = t + q * 256;
    float v = ub[n];
    for (int tt = 0; tt < nhist; ++tt)
      if (n == histsh[tt]) v = kNeg;
    uval[q] = v;
    if (v > lmax) { lmax = v; lidx = n; }
  }
  red[t] = lmax; redi[t] = lidx;
  __syncthreads();
  for (int off = 128; off >= 1; off >>= 1) {
    if (t < off) {
      float o = red[t + off]; int oi = redi[t + off];
      if (o > red[t] || (o == red[t] && oi < redi[t])) { red[t] = o; redi[t] = oi; }
    }
    __syncthreads();
  }
  float mu = red[0];
  int gidx = redi[0];
  __syncthreads();
  float ssum = 0.f;
  #pragma unroll
  for (int q = 0; q < 8; ++q) ssum += expf(uval[q] - mu);
  red[t] = ssum;
  __syncthreads();
  for (int off = 128; off >= 1; off >>= 1) {
    if (t < off) red[t] += red[t + off];
    __syncthreads();
  }
  float Z = red[0];
  float lse = mu + logf(Z);
  __syncthreads();
  float ent = 0.f;
  #pragma unroll
  for (int q = 0; q < 8; ++q) {
    float logp = uval[q] - lse;
    float p = expf(logp);
    if (p > 0.f) ent -= p * logp;
  }
  red[t] = ent;
  __syncthreads();
  for (int off = 128; off >= 1; off >>= 1) {
    if (t < off) red[t] += red[t + off];
    __syncthreads();
  }
  ent_out = red[0];
  gidx_out = gidx;
  lse_out = lse;
  __syncthreads();  // red/redi safe for reuse
}

// ---- fused iteration: select(ts-1)+chain(ts) [blocks 0..511] -> flag ->
//      uscore(ts) [all 2048 blocks]. Single dispatch per iteration. ----
__global__ __launch_bounds__(256, 8) void k_iter(const float* __restrict__ enc,
                                                 const float* __restrict__ w,
                                                 const float* __restrict__ Sacc,
                                                 const float* __restrict__ W0,
                                                 const float* __restrict__ BT,
                                                 const float* __restrict__ cvec,
                                                 float* __restrict__ rpart,
                                                 float* __restrict__ u,
                                                 int* __restrict__ hist,
                                                 float* __restrict__ out,
                                                 unsigned* __restrict__ flag,
                                                 int ts) {
  int bid = blockIdx.x, t = threadIdx.x;
  __shared__ float red[256];
  __shared__ int redi[256];
  __shared__ int histsh[16];
  __shared__ float sh[Dc];
  __shared__ __align__(16) float rsm[Dc];

  // ---- producer phase: blocks 0..511 = (b,h) ----
  if (bid < Bc * Hc) {
    int b = bid >> 3, h = bid & 7;
    if (t < 16) histsh[t] = (t < ts - 1) ? hist[b * 16 + t] : -1;
    __syncthreads();
    if (ts > 0) {
      int sel_t = ts - 1;
      int gidx; float lse, ent;
      select_core(u + (size_t)b * Nc, histsh, sel_t, t, red, redi, gidx, lse, ent);
      if (h == 0 && t == 0) {
        float pi = expf(u[(size_t)b * Nc + gidx] - lse);
        out[b * Sc + sel_t] = (float)gidx;
        out[Bc * Sc + b * Sc + sel_t] = pi;
        if (sel_t == 0) out[2 * Bc * Sc + b] = ent;
        else out[2 * Bc * Sc + b] += ent;
        hist[b * 16 + sel_t] = gidx;
      }
      if (t == 0) histsh[sel_t] = gidx;
      __syncthreads();
    }
    float se = Sacc[((size_t)b * Hc + h) * Dc + t];
    float Wh = W0[b * Hc + h];
    for (int tt = 0; tt < ts; ++tt) {
      int j = histsh[tt];
      float wv = w[((size_t)b * Hc + h) * Nc + j];
      se -= wv * enc[((size_t)b * Nc + j) * Dc + t];
      Wh -= wv;
    }
    sh[t] = se / Wh;
    __syncthreads();
    const float* bt = BT + (size_t)h * Dc * Dc + t;
    float a0 = 0.f, a1 = 0.f, a2 = 0.f, a3 = 0.f;
    #pragma unroll 4
    for (int e = 0; e < Dc; e += 4) {
      a0 += bt[(size_t)e * Dc] * sh[e];
      a1 += bt[(size_t)(e + 1) * Dc] * sh[e + 1];
      a2 += bt[(size_t)(e + 2) * Dc] * sh[e + 2];
      a3 += bt[(size_t)(e + 3) * Dc] * sh[e + 3];
    }
    rpart[((size_t)b * Hc + h) * Dc + t] = (a0 + a1) + (a2 + a3);
    __threadfence();     // make rpart visible at agent scope
    __syncthreads();     // all lanes' stores issued+fenced
    if (t == 0) atomicAdd(&flag[b], 1u);   // device-scope release counter
  }

  // ---- consumer phase: uscore, item = bid (b2, ng), 4 threads/row ----
  {
    int b2 = bid >> 5, ng = bid & 31;
    unsigned tgt = 8u * (unsigned)(ts + 1);
    if (t == 0) {
      while (__hip_atomic_load(&flag[b2], __ATOMIC_RELAXED, __HIP_MEMORY_SCOPE_AGENT) < tgt)
        __builtin_amdgcn_s_sleep(2);
    }
    __syncthreads();
    __threadfence();     // acquire: no stale rpart from caches
    {
      float vsum = cvec[t];
      #pragma unroll
      for (int h = 0; h < Hc; ++h) vsum += rpart[((size_t)b2 * Hc + h) * Dc + t];
      rsm[t] = vsum;
    }
    __syncthreads();
    int row = t >> 2, q = t & 3;
    int n = ng * 64 + row;
    const float4* rowp = reinterpret_cast<const float4*>(enc + ((size_t)b2 * Nc + n) * Dc);
    const float4* r4 = reinterpret_cast<const float4*>(rsm);
    float acc = 0.f;
    #pragma unroll
    for (int i = 0; i < 16; ++i) {
      int d4 = i * 4 + q;
      const float4 e = rowp[d4];
      const float4 rr = r4[d4];
      acc += e.x * rr.x + e.y * rr.y + e.z * rr.z + e.w * rr.w;
    }
    acc += __shfl_xor(acc, 1);
    acc += __shfl_xor(acc, 2);
    if (q == 0) u[(size_t)b2 * Nc + n] = kClip * tanhf(kScale2 * acc);
  }
}

// ---- final select (step Sc-1) ----
__global__ __launch_bounds__(256) void k_selfinal(const float* __restrict__ u,
                                                  const int* __restrict__ hist,
                                                  float* __restrict__ out) {
  int b = blockIdx.x, t = threadIdx.x;
  __shared__ float red[256];
  __shared__ int redi[256];
  __shared__ int histsh[16];
  if (t < 16) histsh[t] = (t < Sc - 1) ? hist[b * 16 + t] : -1;
  __syncthreads();
  int gidx; float lse, ent;
  select_core(u + (size_t)b * Nc, histsh, Sc - 1, t, red, redi, gidx, lse, ent);
  if (t == 0) {
    float pi = expf(u[(size_t)b * Nc + gidx] - lse);
    out[b * Sc + (Sc - 1)] = (float)gidx;
    out[Bc * Sc + b * Sc + (Sc - 1)] = pi;
    out[2 * Bc * Sc + b] += ent;
  }
}

extern "C" void kernel_launch(void* const* d_in, const int* in_sizes, int n_in,
                              void* d_out, int out_size, void* d_ws, size_t ws_size,
                              hipStream_t stream) {
  (void)in_sizes; (void)n_in; (void)out_size; (void)ws_size;
  const float* enc  = (const float*)d_in[0];
  const float* in_w = (const float*)d_in[1];
  const float* in_b = (const float*)d_in[2];
  const float* ow   = (const float*)d_in[3];
  const float* ob   = (const float*)d_in[4];
  const float* swq  = (const float*)d_in[5];
  const float* swk  = (const float*)d_in[6];
  float* out = (float*)d_out;

  float* ws = (float*)d_ws;
  size_t off = 0;
  auto alloc = [&](size_t n) { float* p = ws + off; off += n; return p; };
  float* hpart = alloc((size_t)Bc * 32 * Dc);
  float* g     = alloc((size_t)Bc * Hc * Dc);
  float* c     = alloc((size_t)Bc * Hc);
  float* s     = alloc((size_t)Bc * Hc * Nc);
  float* mrow  = alloc((size_t)Bc * Hc);
  float* w     = alloc((size_t)Bc * Hc * Nc);
  float* W0    = alloc((size_t)Bc * Hc);
  float* Spart = alloc((size_t)Bc * 8 * Hc * Dc);
  float* Sacc  = alloc((size_t)Bc * Hc * Dc);
  float* M1    = alloc((size_t)Dc * Dc);
  float* m1b   = alloc(Dc);
  float* Aout  = alloc((size_t)Dc * Dc);
  float* cvec  = alloc(Dc);
  float* BT    = alloc((size_t)Hc * Dc * Dc);
  float* rpart = alloc((size_t)Bc * Hc * Dc);
  float* u     = alloc((size_t)Bc * Nc);
  int* hist    = (int*)alloc((size_t)Bc * 16);
  unsigned* flag = (unsigned*)alloc(Bc);

  k_hmean_part<<<Bc * 32, 256, 0, stream>>>(enc, hpart);
  k_qgc<<<Bc, 256, 0, stream>>>(hpart, in_w, in_b, g, c);
  k_A1<<<Dc, 256, 0, stream>>>(swq, ow, ob, M1, m1b);
  k_A2<<<Dc, 256, 0, stream>>>(swk, M1, m1b, in_b, Aout, cvec);
  k_A3<<<Hc * 8, 256, 0, stream>>>(Aout, in_w, BT);
  k_scores<<<Bc * 16, 256, 0, stream>>>(enc, g, c, s);
  k_rowmax<<<Bc * Hc, 256, 0, stream>>>(s, mrow);
  k_S0part<<<Bc * 8, 256, 0, stream>>>(enc, s, mrow, w, Spart);
  k_S0red<<<Bc * Hc, 256, 0, stream>>>(Spart, w, Sacc, W0, flag);

  for (int t = 0; t < Sc; ++t) {
    k_iter<<<Bc * 32, 256, 0, stream>>>(enc, w, Sacc, W0, BT, cvec, rpart, u,
                                        hist, out, flag, t);
  }
  k_selfinal<<<Bc, 256, 0, stream>>>(u, hist, out);
}

// Round 9
// 671.805 us; speedup vs baseline: 4.2746x; 4.2746x over previous
//
#include <hip/hip_runtime.h>
#include <hip/hip_bf16.h>
#include <math.h>

namespace {
constexpr int Bc = 64, Nc = 2048, Dc = 256, Hc = 8, DHc = 32, Sc = 10;
constexpr float kNeg = -1000000000.0f;
constexpr float kClip = 10.0f;
constexpr float kScale = 0.17677669529663687f;   // 1/sqrt(32)
constexpr float kScale2 = 0.0625f;               // 1/sqrt(256)
}

// ---- h_mean partials: 2048 blocks, 64-row chunks ----
__global__ __launch_bounds__(256) void k_hmean_part(const float* __restrict__ enc,
                                                    float* __restrict__ hpart) {
  int b = blockIdx.x >> 5, c = blockIdx.x & 31, d = threadIdx.x;
  const float* p = enc + ((size_t)b * Nc + c * 64) * Dc + d;
  float s = 0.f;
  #pragma unroll 8
  for (int n = 0; n < 64; ++n) s += p[(size_t)n * Dc];
  hpart[(size_t)blockIdx.x * Dc + d] = s;
}

// ---- qgc (folds hmean reduction): q, g, c ----
__global__ __launch_bounds__(256) void k_qgc(const float* __restrict__ hpart,
                                             const float* __restrict__ w_in,
                                             const float* __restrict__ b_in,
                                             float* __restrict__ g, float* __restrict__ c) {
  int b = blockIdx.x, t = threadIdx.x;
  __shared__ float hm[Dc];
  __shared__ float qsh[Dc];
  {
    float s = 0.f;
    for (int cc = 0; cc < 32; ++cc) s += hpart[(size_t)(b * 32 + cc) * Dc + t];
    hm[t] = s * (1.0f / Nc);
  }
  __syncthreads();
  {
    const float* row = w_in + (size_t)t * Dc;  // Wq row t
    float acc = b_in[t];
    for (int d = 0; d < Dc; ++d) acc += row[d] * hm[d];
    qsh[t] = acc;
  }
  __syncthreads();
  for (int h = 0; h < Hc; ++h) {
    float acc = 0.f;
    const float* wk = w_in + (size_t)(Dc + h * DHc) * Dc + t;  // Wk rows, col t
    const float* qh = qsh + h * DHc;
    #pragma unroll 8
    for (int i = 0; i < DHc; ++i) acc += qh[i] * wk[(size_t)i * Dc];
    g[((size_t)b * Hc + h) * Dc + t] = acc;
  }
  if (t < Hc) {
    float acc = 0.f;
    for (int i = 0; i < DHc; ++i) acc += qsh[t * DHc + i] * b_in[Dc + t * DHc + i];
    c[b * Hc + t] = acc;
  }
}

// ---- setup: M1 = sha_wq @ out_w ; m1b = sha_wq @ out_b ----
__global__ __launch_bounds__(256) void k_A1(const float* __restrict__ swq,
                                            const float* __restrict__ ow,
                                            const float* __restrict__ ob,
                                            float* __restrict__ M1, float* __restrict__ m1b) {
  int i = blockIdx.x, e = threadIdx.x;
  __shared__ float row[Dc];
  __shared__ float red[256];
  row[e] = swq[(size_t)i * Dc + e];
  __syncthreads();
  float acc = 0.f;
  #pragma unroll 4
  for (int k = 0; k < Dc; ++k) acc += row[k] * ow[(size_t)k * Dc + e];
  M1[(size_t)i * Dc + e] = acc;
  red[e] = row[e] * ob[e];
  __syncthreads();
  for (int off = 128; off >= 1; off >>= 1) {
    if (e < off) red[e] += red[e + off];
    __syncthreads();
  }
  if (e == 0) m1b[i] = red[0];
}

// ---- setup: AT[e][d] = A[d][e], A = sha_wk^T @ M1 ; cvec2 = sha_wk^T @ m1b ----
__global__ __launch_bounds__(256) void k_A2(const float* __restrict__ swk,
                                            const float* __restrict__ M1,
                                            const float* __restrict__ m1b,
                                            float* __restrict__ AT, float* __restrict__ cvec2) {
  int d = blockIdx.x, e = threadIdx.x;
  __shared__ float col[Dc];
  __shared__ float red[256];
  col[e] = swk[(size_t)e * Dc + d];
  __syncthreads();
  float acc = 0.f;
  #pragma unroll 4
  for (int k = 0; k < Dc; ++k) acc += col[k] * M1[(size_t)k * Dc + e];
  AT[(size_t)e * Dc + d] = acc;           // transposed store
  red[e] = col[e] * m1b[e];
  __syncthreads();
  for (int off = 128; off >= 1; off >>= 1) {
    if (e < off) red[e] += red[e + off];
    __syncthreads();
  }
  if (e == 0) cvec2[d] = red[0];
}

// ---- scores: 2 threads per row, 1024 blocks ----
__global__ __launch_bounds__(256) void k_scores(const float* __restrict__ enc,
                                                const float* __restrict__ g,
                                                const float* __restrict__ c,
                                                float* __restrict__ s) {
  int b = blockIdx.x >> 4, nt = blockIdx.x & 15, t = threadIdx.x;
  __shared__ __align__(16) float gsm[Hc * Dc];
  __shared__ float csm[Hc];
  for (int k = t; k < Hc * Dc; k += 256) gsm[k] = g[(size_t)b * Hc * Dc + k];
  if (t < Hc) csm[t] = c[b * Hc + t];
  __syncthreads();
  int row = t >> 1, half = t & 1;
  int n = nt * 128 + row;
  const float4* rowp = reinterpret_cast<const float4*>(enc + ((size_t)b * Nc + n) * Dc);
  float acc[Hc] = {};
  #pragma unroll 8
  for (int i = 0; i < 32; ++i) {
    int d4 = i * 2 + half;
    const float4 e = rowp[d4];
    #pragma unroll
    for (int h = 0; h < Hc; ++h) {
      const float4 g4 = *reinterpret_cast<const float4*>(gsm + h * Dc + d4 * 4);
      acc[h] += e.x * g4.x + e.y * g4.y + e.z * g4.z + e.w * g4.w;
    }
  }
  #pragma unroll
  for (int h = 0; h < Hc; ++h) acc[h] += __shfl_xor(acc[h], 1);
  if (half == 0) {
    #pragma unroll
    for (int h = 0; h < Hc; ++h)
      s[((size_t)b * Hc + h) * Nc + n] = kScale * (acc[h] + csm[h]);
  }
}

// ---- rowmax per (b,h) ----
__global__ __launch_bounds__(256) void k_rowmax(const float* __restrict__ s,
                                                float* __restrict__ mrow) {
  int bh = blockIdx.x, t = threadIdx.x;
  __shared__ float red[256];
  float m = -3.0e38f;
  #pragma unroll
  for (int q = 0; q < 8; ++q) m = fmaxf(m, s[(size_t)bh * Nc + q * 256 + t]);
  red[t] = m;
  __syncthreads();
  for (int off = 128; off >= 1; off >>= 1) {
    if (t < off) red[t] = fmaxf(red[t], red[t + off]);
    __syncthreads();
  }
  if (t == 0) mrow[bh] = red[0];
}

// ---- S0 partials, 16 chunks of 128 rows (+exp fold: w = exp(s-m)) ----
__global__ __launch_bounds__(256) void k_S0part(const float* __restrict__ enc,
                                                const float* __restrict__ s,
                                                const float* __restrict__ mrow,
                                                float* __restrict__ w,
                                                float* __restrict__ Spart) {
  int b = blockIdx.x >> 4, cid = blockIdx.x & 15, t = threadIdx.x;
  __shared__ float wsm[Hc * 128];
  for (int k = t; k < Hc * 128; k += 256) {
    int h = k >> 7, ni = k & 127;
    float m = mrow[b * Hc + h];
    float e = expf(s[((size_t)b * Hc + h) * Nc + cid * 128 + ni] - m);
    wsm[k] = e;
    w[((size_t)b * Hc + h) * Nc + cid * 128 + ni] = e;
  }
  __syncthreads();
  float acc[Hc] = {};
  const float* ep = enc + ((size_t)b * Nc + cid * 128) * Dc + t;
  for (int ni = 0; ni < 128; ++ni) {
    float ev = ep[(size_t)ni * Dc];
    #pragma unroll
    for (int h = 0; h < Hc; ++h) acc[h] += wsm[h * 128 + ni] * ev;
  }
  #pragma unroll
  for (int h = 0; h < Hc; ++h)
    Spart[(((size_t)b * 16 + cid) * Hc + h) * Dc + t] = acc[h];
}

// ---- S0 reduce + W0 = sum_n w ----
__global__ __launch_bounds__(256) void k_S0red(const float* __restrict__ Spart,
                                               const float* __restrict__ w,
                                               float* __restrict__ Sacc,
                                               float* __restrict__ W0) {
  int b = blockIdx.x >> 3, h = blockIdx.x & 7, t = threadIdx.x;
  __shared__ float red[256];
  float acc = 0.f;
  for (int cid = 0; cid < 16; ++cid)
    acc += Spart[(((size_t)b * 16 + cid) * Hc + h) * Dc + t];
  Sacc[((size_t)b * Hc + h) * Dc + t] = acc;
  float ws = 0.f;
  #pragma unroll
  for (int q = 0; q < 8; ++q) ws += w[((size_t)b * Hc + h) * Nc + q * 256 + t];
  red[t] = ws;
  __syncthreads();
  for (int off = 128; off >= 1; off >>= 1) {
    if (t < off) red[t] += red[t + off];
    __syncthreads();
  }
  if (t == 0) W0[b * Hc + h] = red[0];
}

// ---- shared select core: masked log-softmax + argmax + entropy ----
__device__ __forceinline__ void select_core(const float* __restrict__ ub,
                                            const int* histsh, int nhist, int t,
                                            float* red, int* redi,
                                            int& gidx_out, float& lse_out, float& ent_out) {
  float uval[8];
  float lmax = -3.0e38f;
  int lidx = 0;
  #pragma unroll
  for (int q = 0; q < 8; ++q) {
    int n = t + q * 256;
    float v = ub[n];
    for (int tt = 0; tt < nhist; ++tt)
      if (n == histsh[tt]) v = kNeg;
    uval[q] = v;
    if (v > lmax) { lmax = v; lidx = n; }
  }
  red[t] = lmax; redi[t] = lidx;
  __syncthreads();
  for (int off = 128; off >= 1; off >>= 1) {
    if (t < off) {
      float o = red[t + off]; int oi = redi[t + off];
      if (o > red[t] || (o == red[t] && oi < redi[t])) { red[t] = o; redi[t] = oi; }
    }
    __syncthreads();
  }
  float mu = red[0];
  int gidx = redi[0];
  __syncthreads();
  float ssum = 0.f;
  #pragma unroll
  for (int q = 0; q < 8; ++q) ssum += expf(uval[q] - mu);
  red[t] = ssum;
  __syncthreads();
  for (int off = 128; off >= 1; off >>= 1) {
    if (t < off) red[t] += red[t + off];
    __syncthreads();
  }
  float Z = red[0];
  float lse = mu + logf(Z);
  __syncthreads();
  float ent = 0.f;
  #pragma unroll
  for (int q = 0; q < 8; ++q) {
    float logp = uval[q] - lse;
    float p = expf(logp);
    if (p > 0.f) ent -= p * logp;
  }
  red[t] = ent;
  __syncthreads();
  for (int off = 128; off >= 1; off >>= 1) {
    if (t < off) red[t] += red[t + off];
    __syncthreads();
  }
  ent_out = red[0];
  gidx_out = gidx;
  lse_out = lse;
  __syncthreads();  // red/redi safe for reuse
}

// ---- fused select(ts-1) + chain(ts): ONE block per b.
//      chain: sh = (S-removals)/W -> ctx = Wv.sh + bv -> r = AT^T.ctx + cvec2 ----
__global__ __launch_bounds__(256) void k_selchain(const float* __restrict__ u,
                                                  int* __restrict__ hist,
                                                  float* __restrict__ out,
                                                  const float* __restrict__ Sacc,
                                                  const float* __restrict__ W0,
                                                  const float* __restrict__ w,
                                                  const float* __restrict__ enc,
                                                  const float* __restrict__ w_in,
                                                  const float* __restrict__ b_in,
                                                  const float* __restrict__ AT,
                                                  const float* __restrict__ cvec2,
                                                  float* __restrict__ r, int ts) {
  int b = blockIdx.x, t = threadIdx.x;
  __shared__ float red[256];
  __shared__ int redi[256];
  __shared__ int histsh[16];
  __shared__ float sh[Hc * Dc];
  __shared__ float ctx[Dc];
  if (t < 16) histsh[t] = (t < ts - 1) ? hist[b * 16 + t] : -1;
  __syncthreads();

  if (ts > 0) {
    int sel_t = ts - 1;
    int gidx; float lse, ent;
    select_core(u + (size_t)b * Nc, histsh, sel_t, t, red, redi, gidx, lse, ent);
    if (t == 0) {
      float pi = expf(u[(size_t)b * Nc + gidx] - lse);
      out[b * Sc + sel_t] = (float)gidx;
      out[Bc * Sc + b * Sc + sel_t] = pi;
      if (sel_t == 0) out[2 * Bc * Sc + b] = ent;
      else out[2 * Bc * Sc + b] += ent;
      hist[b * 16 + sel_t] = gidx;
      histsh[sel_t] = gidx;
    }
    __syncthreads();
  }

  // replay: sh[h][t] = (Sacc - removals)/W
  #pragma unroll
  for (int h = 0; h < Hc; ++h) {
    float se = Sacc[((size_t)b * Hc + h) * Dc + t];
    float Wh = W0[b * Hc + h];
    for (int tt = 0; tt < ts; ++tt) {
      int j = histsh[tt];
      float wv = w[((size_t)b * Hc + h) * Nc + j];
      se -= wv * enc[((size_t)b * Nc + j) * Dc + t];
      Wh -= wv;
    }
    sh[h * Dc + t] = se / Wh;
  }
  __syncthreads();

  // ctx[t] = Wv_row(t) . sh_head(t>>5) + bv[t]
  {
    int h2 = t >> 5;
    const float4* row = reinterpret_cast<const float4*>(w_in + (size_t)(2 * Dc + t) * Dc);
    const float* shh = sh + h2 * Dc;
    float a0 = 0.f, a1 = 0.f, a2 = 0.f, a3 = 0.f;
    #pragma unroll 8
    for (int d4 = 0; d4 < 64; ++d4) {
      const float4 rr = row[d4];
      a0 += rr.x * shh[d4 * 4 + 0];
      a1 += rr.y * shh[d4 * 4 + 1];
      a2 += rr.z * shh[d4 * 4 + 2];
      a3 += rr.w * shh[d4 * 4 + 3];
    }
    ctx[t] = (a0 + a1) + (a2 + a3) + b_in[2 * Dc + t];
  }
  __syncthreads();

  // r[t] = cvec2[t] + sum_k AT[k][t]*ctx[k]   (coalesced over t)
  {
    float acc = cvec2[t];
    const float* at = AT + t;
    #pragma unroll 8
    for (int k = 0; k < Dc; ++k) acc += at[(size_t)k * Dc] * ctx[k];
    r[b * Dc + t] = acc;
  }
}

// ---- u scores: 8 threads per row, 4096 blocks ----
__global__ __launch_bounds__(256) void k_uscore(const float* __restrict__ enc,
                                                const float* __restrict__ r,
                                                float* __restrict__ u) {
  int b = blockIdx.x >> 6, ng = blockIdx.x & 63, t = threadIdx.x;
  __shared__ __align__(16) float rsm[Dc];
  rsm[t] = r[b * Dc + t];
  __syncthreads();
  int row = t >> 3, q = t & 7;
  int n = ng * 32 + row;
  const float4* rowp = reinterpret_cast<const float4*>(enc + ((size_t)b * Nc + n) * Dc);
  const float4* r4 = reinterpret_cast<const float4*>(rsm);
  float acc = 0.f;
  #pragma unroll
  for (int i = 0; i < 8; ++i) {
    int d4 = i * 8 + q;
    const float4 e = rowp[d4];
    const float4 rr = r4[d4];
    acc += e.x * rr.x + e.y * rr.y + e.z * rr.z + e.w * rr.w;
  }
  acc += __shfl_xor(acc, 1);
  acc += __shfl_xor(acc, 2);
  acc += __shfl_xor(acc, 4);
  if (q == 0) u[(size_t)b * Nc + n] = kClip * tanhf(kScale2 * acc);
}

// ---- final select (step Sc-1) ----
__global__ __launch_bounds__(256) void k_selfinal(const float* __restrict__ u,
                                                  const int* __restrict__ hist,
                                                  float* __restrict__ out) {
  int b = blockIdx.x, t = threadIdx.x;
  __shared__ float red[256];
  __shared__ int redi[256];
  __shared__ int histsh[16];
  if (t < 16) histsh[t] = (t < Sc - 1) ? hist[b * 16 + t] : -1;
  __syncthreads();
  int gidx; float lse, ent;
  select_core(u + (size_t)b * Nc, histsh, Sc - 1, t, red, redi, gidx, lse, ent);
  if (t == 0) {
    float pi = expf(u[(size_t)b * Nc + gidx] - lse);
    out[b * Sc + (Sc - 1)] = (float)gidx;
    out[Bc * Sc + b * Sc + (Sc - 1)] = pi;
    out[2 * Bc * Sc + b] += ent;
  }
}

extern "C" void kernel_launch(void* const* d_in, const int* in_sizes, int n_in,
                              void* d_out, int out_size, void* d_ws, size_t ws_size,
                              hipStream_t stream) {
  (void)in_sizes; (void)n_in; (void)out_size; (void)ws_size;
  const float* enc  = (const float*)d_in[0];
  const float* in_w = (const float*)d_in[1];
  const float* in_b = (const float*)d_in[2];
  const float* ow   = (const float*)d_in[3];
  const float* ob   = (const float*)d_in[4];
  const float* swq  = (const float*)d_in[5];
  const float* swk  = (const float*)d_in[6];
  float* out = (float*)d_out;

  float* ws = (float*)d_ws;
  size_t off = 0;
  auto alloc = [&](size_t n) { float* p = ws + off; off += n; return p; };
  float* hpart = alloc((size_t)Bc * 32 * Dc);
  float* g     = alloc((size_t)Bc * Hc * Dc);
  float* c     = alloc((size_t)Bc * Hc);
  float* s     = alloc((size_t)Bc * Hc * Nc);
  float* mrow  = alloc((size_t)Bc * Hc);
  float* w     = alloc((size_t)Bc * Hc * Nc);
  float* W0    = alloc((size_t)Bc * Hc);
  float* Spart = alloc((size_t)Bc * 16 * Hc * Dc);
  float* Sacc  = alloc((size_t)Bc * Hc * Dc);
  float* M1    = alloc((size_t)Dc * Dc);
  float* m1b   = alloc(Dc);
  float* AT    = alloc((size_t)Dc * Dc);
  float* cvec2 = alloc(Dc);
  float* r     = alloc((size_t)Bc * Dc);
  float* u     = alloc((size_t)Bc * Nc);
  int* hist    = (int*)alloc((size_t)Bc * 16);

  k_hmean_part<<<Bc * 32, 256, 0, stream>>>(enc, hpart);
  k_qgc<<<Bc, 256, 0, stream>>>(hpart, in_w, in_b, g, c);
  k_A1<<<Dc, 256, 0, stream>>>(swq, ow, ob, M1, m1b);
  k_A2<<<Dc, 256, 0, stream>>>(swk, M1, m1b, AT, cvec2);
  k_scores<<<Bc * 16, 256, 0, stream>>>(enc, g, c, s);
  k_rowmax<<<Bc * Hc, 256, 0, stream>>>(s, mrow);
  k_S0part<<<Bc * 16, 256, 0, stream>>>(enc, s, mrow, w, Spart);
  k_S0red<<<Bc * Hc, 256, 0, stream>>>(Spart, w, Sacc, W0);

  for (int t = 0; t < Sc; ++t) {
    k_selchain<<<Bc, 256, 0, stream>>>(u, hist, out, Sacc, W0, w, enc,
                                       in_w, in_b, AT, cvec2, r, t);
    k_uscore<<<Bc * 64, 256, 0, stream>>>(enc, r, u);
  }
  k_selfinal<<<Bc, 256, 0, stream>>>(u, hist, out);
}

// Round 10
// 525.616 us; speedup vs baseline: 5.4634x; 1.2781x over previous
//
#include <hip/hip_runtime.h>
#include <hip/hip_bf16.h>
#include <math.h>

namespace {
constexpr int Bc = 64, Nc = 2048, Dc = 256, Hc = 8, DHc = 32, Sc = 10;
constexpr float kNeg = -1000000000.0f;
constexpr float kClip = 10.0f;
constexpr float kScale = 0.17677669529663687f;   // 1/sqrt(32)
constexpr float kScale2 = 0.0625f;               // 1/sqrt(256)

__device__ __forceinline__ unsigned fkey(float x) {
  unsigned b = __float_as_uint(x);
  return (b & 0x80000000u) ? ~b : (b | 0x80000000u);
}
__device__ __forceinline__ float fdec(unsigned k) {
  unsigned b = (k & 0x80000000u) ? (k ^ 0x80000000u) : ~k;
  return __uint_as_float(b);
}
}

// ---- h_mean partials: 2048 blocks, 64-row chunks ----
__global__ __launch_bounds__(256) void k_hmean_part(const float* __restrict__ enc,
                                                    float* __restrict__ hpart) {
  int b = blockIdx.x >> 5, c = blockIdx.x & 31, d = threadIdx.x;
  const float* p = enc + ((size_t)b * Nc + c * 64) * Dc + d;
  float s = 0.f;
  #pragma unroll 8
  for (int n = 0; n < 64; ++n) s += p[(size_t)n * Dc];
  hpart[(size_t)blockIdx.x * Dc + d] = s;
}

// ---- qgc (folds hmean reduction): q, g, c ; init mrow_u ----
__global__ __launch_bounds__(256) void k_qgc(const float* __restrict__ hpart,
                                             const float* __restrict__ w_in,
                                             const float* __restrict__ b_in,
                                             float* __restrict__ g, float* __restrict__ c,
                                             unsigned* __restrict__ mrow_u) {
  int b = blockIdx.x, t = threadIdx.x;
  __shared__ float hm[Dc];
  __shared__ float qsh[Dc];
  if (t < Hc) mrow_u[b * Hc + t] = 0u;   // key 0 < any real value's key
  {
    float s = 0.f;
    for (int cc = 0; cc < 32; ++cc) s += hpart[(size_t)(b * 32 + cc) * Dc + t];
    hm[t] = s * (1.0f / Nc);
  }
  __syncthreads();
  {
    const float* row = w_in + (size_t)t * Dc;  // Wq row t
    float acc = b_in[t];
    for (int d = 0; d < Dc; ++d) acc += row[d] * hm[d];
    qsh[t] = acc;
  }
  __syncthreads();
  for (int h = 0; h < Hc; ++h) {
    float acc = 0.f;
    const float* wk = w_in + (size_t)(Dc + h * DHc) * Dc + t;  // Wk rows, col t
    const float* qh = qsh + h * DHc;
    #pragma unroll 8
    for (int i = 0; i < DHc; ++i) acc += qh[i] * wk[(size_t)i * Dc];
    g[((size_t)b * Hc + h) * Dc + t] = acc;
  }
  if (t < Hc) {
    float acc = 0.f;
    for (int i = 0; i < DHc; ++i) acc += qsh[t * DHc + i] * b_in[Dc + t * DHc + i];
    c[b * Hc + t] = acc;
  }
}

// ---- setup: M1 = sha_wq @ out_w ; m1b = sha_wq @ out_b ----
__global__ __launch_bounds__(256) void k_A1(const float* __restrict__ swq,
                                            const float* __restrict__ ow,
                                            const float* __restrict__ ob,
                                            float* __restrict__ M1, float* __restrict__ m1b) {
  int i = blockIdx.x, e = threadIdx.x;
  __shared__ float row[Dc];
  __shared__ float red[256];
  row[e] = swq[(size_t)i * Dc + e];
  __syncthreads();
  float acc = 0.f;
  #pragma unroll 4
  for (int k = 0; k < Dc; ++k) acc += row[k] * ow[(size_t)k * Dc + e];
  M1[(size_t)i * Dc + e] = acc;
  red[e] = row[e] * ob[e];
  __syncthreads();
  for (int off = 128; off >= 1; off >>= 1) {
    if (e < off) red[e] += red[e + off];
    __syncthreads();
  }
  if (e == 0) m1b[i] = red[0];
}

// ---- setup: A = sha_wk^T @ M1 ; cvec = A@bv + sha_wk^T@m1b ----
__global__ __launch_bounds__(256) void k_A2(const float* __restrict__ swk,
                                            const float* __restrict__ M1,
                                            const float* __restrict__ m1b,
                                            const float* __restrict__ b_in,
                                            float* __restrict__ Aout, float* __restrict__ cvec) {
  int d = blockIdx.x, e = threadIdx.x;
  __shared__ float col[Dc];
  __shared__ float red[256];
  col[e] = swk[(size_t)e * Dc + d];
  __syncthreads();
  float acc = 0.f;
  #pragma unroll 4
  for (int k = 0; k < Dc; ++k) acc += col[k] * M1[(size_t)k * Dc + e];
  Aout[(size_t)d * Dc + e] = acc;
  red[e] = acc * b_in[2 * Dc + e] + col[e] * m1b[e];
  __syncthreads();
  for (int off = 128; off >= 1; off >>= 1) {
    if (e < off) red[e] += red[e + off];
    __syncthreads();
  }
  if (e == 0) cvec[d] = red[0];
}

// ---- setup: BT[(h*256+e)*256+d] = sum_i A[d][h*32+i] * Wv[h*32+i][e] ----
__global__ __launch_bounds__(256) void k_A3(const float* __restrict__ Aout,
                                            const float* __restrict__ w_in,
                                            float* __restrict__ BT) {
  int h = blockIdx.x >> 3, et = blockIdx.x & 7, d = threadIdx.x;
  float arow[DHc];
  #pragma unroll
  for (int i = 0; i < DHc; ++i) arow[i] = Aout[(size_t)d * Dc + h * DHc + i];
  __shared__ float wv[DHc][DHc];
  for (int k = threadIdx.x; k < DHc * DHc; k += 256) {
    int i = k >> 5, j = k & 31;
    wv[i][j] = w_in[(size_t)(2 * Dc + h * DHc + i) * Dc + et * DHc + j];
  }
  __syncthreads();
  for (int j = 0; j < DHc; ++j) {
    float acc = 0.f;
    #pragma unroll
    for (int i = 0; i < DHc; ++i) acc += arow[i] * wv[i][j];
    BT[((size_t)h * Dc + et * DHc + j) * Dc + d] = acc;
  }
}

// ---- scores: 2 threads per row, 1024 blocks; rowmax folded via atomicMax ----
__global__ __launch_bounds__(256) void k_scores(const float* __restrict__ enc,
                                                const float* __restrict__ g,
                                                const float* __restrict__ c,
                                                float* __restrict__ s,
                                                unsigned* __restrict__ mrow_u) {
  int b = blockIdx.x >> 4, nt = blockIdx.x & 15, t = threadIdx.x;
  __shared__ __align__(16) float gsm[Hc * Dc];
  __shared__ float csm[Hc];
  for (int k = t; k < Hc * Dc; k += 256) gsm[k] = g[(size_t)b * Hc * Dc + k];
  if (t < Hc) csm[t] = c[b * Hc + t];
  __syncthreads();
  int row = t >> 1, half = t & 1;
  int n = nt * 128 + row;
  const float4* rowp = reinterpret_cast<const float4*>(enc + ((size_t)b * Nc + n) * Dc);
  float acc[Hc] = {};
  #pragma unroll 8
  for (int i = 0; i < 32; ++i) {
    int d4 = i * 2 + half;
    const float4 e = rowp[d4];
    #pragma unroll
    for (int h = 0; h < Hc; ++h) {
      const float4 g4 = *reinterpret_cast<const float4*>(gsm + h * Dc + d4 * 4);
      acc[h] += e.x * g4.x + e.y * g4.y + e.z * g4.z + e.w * g4.w;
    }
  }
  float sv[Hc];
  #pragma unroll
  for (int h = 0; h < Hc; ++h) {
    acc[h] += __shfl_xor(acc[h], 1);
    sv[h] = kScale * (acc[h] + csm[h]);
  }
  if (half == 0) {
    #pragma unroll
    for (int h = 0; h < Hc; ++h)
      s[((size_t)b * Hc + h) * Nc + n] = sv[h];
  }
  // wave-level max reduce, one atomicMax per (wave, h)
  #pragma unroll
  for (int h = 0; h < Hc; ++h) {
    float m = sv[h];
    #pragma unroll
    for (int off = 32; off >= 2; off >>= 1) m = fmaxf(m, __shfl_xor(m, off));
    if ((t & 63) == 0) atomicMax(&mrow_u[b * Hc + h], fkey(m));
  }
}

// ---- S0 partials, 16 chunks of 128 rows (+exp fold: w = exp(s-m)) ----
__global__ __launch_bounds__(256) void k_S0part(const float* __restrict__ enc,
                                                const float* __restrict__ s,
                                                const unsigned* __restrict__ mrow_u,
                                                float* __restrict__ w,
                                                float* __restrict__ Spart) {
  int b = blockIdx.x >> 4, cid = blockIdx.x & 15, t = threadIdx.x;
  __shared__ float wsm[Hc * 128];
  for (int k = t; k < Hc * 128; k += 256) {
    int h = k >> 7, ni = k & 127;
    float m = fdec(mrow_u[b * Hc + h]);
    float e = expf(s[((size_t)b * Hc + h) * Nc + cid * 128 + ni] - m);
    wsm[k] = e;
    w[((size_t)b * Hc + h) * Nc + cid * 128 + ni] = e;
  }
  __syncthreads();
  float acc[Hc] = {};
  const float* ep = enc + ((size_t)b * Nc + cid * 128) * Dc + t;
  for (int ni = 0; ni < 128; ++ni) {
    float ev = ep[(size_t)ni * Dc];
    #pragma unroll
    for (int h = 0; h < Hc; ++h) acc[h] += wsm[h * 128 + ni] * ev;
  }
  #pragma unroll
  for (int h = 0; h < Hc; ++h)
    Spart[(((size_t)b * 16 + cid) * Hc + h) * Dc + t] = acc[h];
}

// ---- S0 reduce + W0 = sum_n w ----
__global__ __launch_bounds__(256) void k_S0red(const float* __restrict__ Spart,
                                               const float* __restrict__ w,
                                               float* __restrict__ Sacc,
                                               float* __restrict__ W0) {
  int b = blockIdx.x >> 3, h = blockIdx.x & 7, t = threadIdx.x;
  __shared__ float red[256];
  float acc = 0.f;
  for (int cid = 0; cid < 16; ++cid)
    acc += Spart[(((size_t)b * 16 + cid) * Hc + h) * Dc + t];
  Sacc[((size_t)b * Hc + h) * Dc + t] = acc;
  float ws = 0.f;
  #pragma unroll
  for (int q = 0; q < 8; ++q) ws += w[((size_t)b * Hc + h) * Nc + q * 256 + t];
  red[t] = ws;
  __syncthreads();
  for (int off = 128; off >= 1; off >>= 1) {
    if (t < off) red[t] += red[t + off];
    __syncthreads();
  }
  if (t == 0) W0[b * Hc + h] = red[0];
}

// ---- shared select core: masked log-softmax + argmax + entropy ----
__device__ __forceinline__ void select_core(const float* __restrict__ ub,
                                            const int* histsh, int nhist, int t,
                                            float* red, int* redi,
                                            int& gidx_out, float& lse_out, float& ent_out) {
  float uval[8];
  float lmax = -3.0e38f;
  int lidx = 0;
  #pragma unroll
  for (int q = 0; q < 8; ++q) {
    int n = t + q * 256;
    float v = ub[n];
    for (int tt = 0; tt < nhist; ++tt)
      if (n == histsh[tt]) v = kNeg;
    uval[q] = v;
    if (v > lmax) { lmax = v; lidx = n; }
  }
  red[t] = lmax; redi[t] = lidx;
  __syncthreads();
  for (int off = 128; off >= 1; off >>= 1) {
    if (t < off) {
      float o = red[t + off]; int oi = redi[t + off];
      if (o > red[t] || (o == red[t] && oi < redi[t])) { red[t] = o; redi[t] = oi; }
    }
    __syncthreads();
  }
  float mu = red[0];
  int gidx = redi[0];
  __syncthreads();
  float ssum = 0.f;
  #pragma unroll
  for (int q = 0; q < 8; ++q) ssum += expf(uval[q] - mu);
  red[t] = ssum;
  __syncthreads();
  for (int off = 128; off >= 1; off >>= 1) {
    if (t < off) red[t] += red[t + off];
    __syncthreads();
  }
  float Z = red[0];
  float lse = mu + logf(Z);
  __syncthreads();
  float ent = 0.f;
  #pragma unroll
  for (int q = 0; q < 8; ++q) {
    float logp = uval[q] - lse;
    float p = expf(logp);
    if (p > 0.f) ent -= p * logp;
  }
  red[t] = ent;
  __syncthreads();
  for (int off = 128; off >= 1; off >>= 1) {
    if (t < off) red[t] += red[t + off];
    __syncthreads();
  }
  ent_out = red[0];
  gidx_out = gidx;
  lse_out = lse;
  __syncthreads();  // red/redi safe for reuse
}

// ---- fused select(t-1) + chain(t): block per (b,h), select redundant ----
__global__ __launch_bounds__(256) void k_selchain(const float* __restrict__ u,
                                                  int* __restrict__ hist,
                                                  float* __restrict__ out,
                                                  const float* __restrict__ Sacc,
                                                  const float* __restrict__ W0,
                                                  const float* __restrict__ w,
                                                  const float* __restrict__ enc,
                                                  const float* __restrict__ BT,
                                                  float* __restrict__ rpart, int tstep) {
  int b = blockIdx.x >> 3, h = blockIdx.x & 7, t = threadIdx.x;
  __shared__ float red[256];
  __shared__ int redi[256];
  __shared__ int histsh[16];
  __shared__ float sh[Dc];
  if (t < 16) histsh[t] = (t < tstep - 1) ? hist[b * 16 + t] : -1;
  __syncthreads();

  if (tstep > 0) {
    int sel_t = tstep - 1;
    int gidx; float lse, ent;
    select_core(u + (size_t)b * Nc, histsh, sel_t, t, red, redi, gidx, lse, ent);
    if (h == 0 && t == 0) {
      float pi = expf(u[(size_t)b * Nc + gidx] - lse);
      out[b * Sc + sel_t] = (float)gidx;
      out[Bc * Sc + b * Sc + sel_t] = pi;
      if (sel_t == 0) out[2 * Bc * Sc + b] = ent;
      else out[2 * Bc * Sc + b] += ent;
      hist[b * 16 + sel_t] = gidx;
    }
    if (t == 0) histsh[sel_t] = gidx;
    __syncthreads();
  }

  // chain for own head
  float se = Sacc[((size_t)b * Hc + h) * Dc + t];
  float Wh = W0[b * Hc + h];
  for (int tt = 0; tt < tstep; ++tt) {
    int j = histsh[tt];
    float wv = w[((size_t)b * Hc + h) * Nc + j];
    se -= wv * enc[((size_t)b * Nc + j) * Dc + t];
    Wh -= wv;
  }
  sh[t] = se / Wh;
  __syncthreads();
  const float* bt = BT + (size_t)h * Dc * Dc + t;
  float a0 = 0.f, a1 = 0.f, a2 = 0.f, a3 = 0.f;
  #pragma unroll 4
  for (int e = 0; e < Dc; e += 4) {
    a0 += bt[(size_t)e * Dc] * sh[e];
    a1 += bt[(size_t)(e + 1) * Dc] * sh[e + 1];
    a2 += bt[(size_t)(e + 2) * Dc] * sh[e + 2];
    a3 += bt[(size_t)(e + 3) * Dc] * sh[e + 3];
  }
  rpart[((size_t)b * Hc + h) * Dc + t] = (a0 + a1) + (a2 + a3);
}

// ---- u scores: 4 threads per row, 2048 blocks ----
__global__ __launch_bounds__(256) void k_uscore(const float* __restrict__ enc,
                                                const float* __restrict__ rpart,
                                                const float* __restrict__ cvec,
                                                float* __restrict__ u) {
  int b = blockIdx.x >> 5, ng = blockIdx.x & 31, t = threadIdx.x;
  __shared__ __align__(16) float rsm[Dc];
  {
    float vsum = cvec[t];
    #pragma unroll
    for (int h = 0; h < Hc; ++h) vsum += rpart[((size_t)b * Hc + h) * Dc + t];
    rsm[t] = vsum;
  }
  __syncthreads();
  int row = t >> 2, q = t & 3;
  int n = ng * 64 + row;
  const float4* rowp = reinterpret_cast<const float4*>(enc + ((size_t)b * Nc + n) * Dc);
  const float4* r4 = reinterpret_cast<const float4*>(rsm);
  float acc = 0.f;
  #pragma unroll
  for (int i = 0; i < 16; ++i) {
    int d4 = i * 4 + q;
    const float4 e = rowp[d4];
    const float4 rr = r4[d4];
    acc += e.x * rr.x + e.y * rr.y + e.z * rr.z + e.w * rr.w;
  }
  acc += __shfl_xor(acc, 1);
  acc += __shfl_xor(acc, 2);
  if (q == 0) u[(size_t)b * Nc + n] = kClip * tanhf(kScale2 * acc);
}

// ---- final select (step Sc-1) ----
__global__ __launch_bounds__(256) void k_selfinal(const float* __restrict__ u,
                                                  const int* __restrict__ hist,
                                                  float* __restrict__ out) {
  int b = blockIdx.x, t = threadIdx.x;
  __shared__ float red[256];
  __shared__ int redi[256];
  __shared__ int histsh[16];
  if (t < 16) histsh[t] = (t < Sc - 1) ? hist[b * 16 + t] : -1;
  __syncthreads();
  int gidx; float lse, ent;
  select_core(u + (size_t)b * Nc, histsh, Sc - 1, t, red, redi, gidx, lse, ent);
  if (t == 0) {
    float pi = expf(u[(size_t)b * Nc + gidx] - lse);
    out[b * Sc + (Sc - 1)] = (float)gidx;
    out[Bc * Sc + b * Sc + (Sc - 1)] = pi;
    out[2 * Bc * Sc + b] += ent;
  }
}

extern "C" void kernel_launch(void* const* d_in, const int* in_sizes, int n_in,
                              void* d_out, int out_size, void* d_ws, size_t ws_size,
                              hipStream_t stream) {
  (void)in_sizes; (void)n_in; (void)out_size; (void)ws_size;
  const float* enc  = (const float*)d_in[0];
  const float* in_w = (const float*)d_in[1];
  const float* in_b = (const float*)d_in[2];
  const float* ow   = (const float*)d_in[3];
  const float* ob   = (const float*)d_in[4];
  const float* swq  = (const float*)d_in[5];
  const float* swk  = (const float*)d_in[6];
  float* out = (float*)d_out;

  float* ws = (float*)d_ws;
  size_t off = 0;
  auto alloc = [&](size_t n) { float* p = ws + off; off += n; return p; };
  float* hpart = alloc((size_t)Bc * 32 * Dc);
  float* g     = alloc((size_t)Bc * Hc * Dc);
  float* c     = alloc((size_t)Bc * Hc);
  float* s     = alloc((size_t)Bc * Hc * Nc);
  unsigned* mrow_u = (unsigned*)alloc((size_t)Bc * Hc);
  float* w     = alloc((size_t)Bc * Hc * Nc);
  float* W0    = alloc((size_t)Bc * Hc);
  float* Spart = alloc((size_t)Bc * 16 * Hc * Dc);
  float* Sacc  = alloc((size_t)Bc * Hc * Dc);
  float* M1    = alloc((size_t)Dc * Dc);
  float* m1b   = alloc(Dc);
  float* Aout  = alloc((size_t)Dc * Dc);
  float* cvec  = alloc(Dc);
  float* BT    = alloc((size_t)Hc * Dc * Dc);
  float* rpart = alloc((size_t)Bc * Hc * Dc);
  float* u     = alloc((size_t)Bc * Nc);
  int* hist    = (int*)alloc((size_t)Bc * 16);

  k_hmean_part<<<Bc * 32, 256, 0, stream>>>(enc, hpart);
  k_qgc<<<Bc, 256, 0, stream>>>(hpart, in_w, in_b, g, c, mrow_u);
  k_A1<<<Dc, 256, 0, stream>>>(swq, ow, ob, M1, m1b);
  k_A2<<<Dc, 256, 0, stream>>>(swk, M1, m1b, in_b, Aout, cvec);
  k_A3<<<Hc * 8, 256, 0, stream>>>(Aout, in_w, BT);
  k_scores<<<Bc * 16, 256, 0, stream>>>(enc, g, c, s, mrow_u);
  k_S0part<<<Bc * 16, 256, 0, stream>>>(enc, s, mrow_u, w, Spart);
  k_S0red<<<Bc * Hc, 256, 0, stream>>>(Spart, w, Sacc, W0);

  for (int t = 0; t < Sc; ++t) {
    k_selchain<<<Bc * Hc, 256, 0, stream>>>(u, hist, out, Sacc, W0, w, enc, BT, rpart, t);
    k_uscore<<<Bc * 32, 256, 0, stream>>>(enc, rpart, cvec, u);
  }
  k_selfinal<<<Bc, 256, 0, stream>>>(u, hist, out);
}

// Round 11
// 508.694 us; speedup vs baseline: 5.6452x; 1.0333x over previous
//
#include <hip/hip_runtime.h>
#include <hip/hip_bf16.h>
#include <math.h>

namespace {
constexpr int Bc = 64, Nc = 2048, Dc = 256, Hc = 8, DHc = 32, Sc = 10;
constexpr float kNeg = -1000000000.0f;
constexpr float kClip = 10.0f;
constexpr float kScale = 0.17677669529663687f;   // 1/sqrt(32)
constexpr float kScale2 = 0.0625f;               // 1/sqrt(256)
}

// ---- h_mean partials: 512 blocks, 256-row chunks, float4 loads ----
__global__ __launch_bounds__(256) void k_hmean_part(const float* __restrict__ enc,
                                                    float* __restrict__ hpart) {
  int b = blockIdx.x >> 3, c = blockIdx.x & 7, t = threadIdx.x;
  int lane = t & 63, wv = t >> 6;
  __shared__ __align__(16) float part[4][Dc];
  const float4* p = reinterpret_cast<const float4*>(
      enc + ((size_t)b * Nc + c * 256 + wv * 64) * Dc) + lane;
  float4 s; s.x = 0.f; s.y = 0.f; s.z = 0.f; s.w = 0.f;
  #pragma unroll 8
  for (int i = 0; i < 64; ++i) {
    const float4 e = p[(size_t)i * 64];
    s.x += e.x; s.y += e.y; s.z += e.z; s.w += e.w;
  }
  *reinterpret_cast<float4*>(&part[wv][lane * 4]) = s;
  __syncthreads();
  hpart[(size_t)blockIdx.x * Dc + t] =
      part[0][t] + part[1][t] + part[2][t] + part[3][t];
}

// ---- qgc (folds hmean reduction): q, g, c ----
__global__ __launch_bounds__(256) void k_qgc(const float* __restrict__ hpart,
                                             const float* __restrict__ w_in,
                                             const float* __restrict__ b_in,
                                             float* __restrict__ g, float* __restrict__ c) {
  int b = blockIdx.x, t = threadIdx.x;
  __shared__ float hm[Dc];
  __shared__ float qsh[Dc];
  {
    float s = 0.f;
    for (int cc = 0; cc < 8; ++cc) s += hpart[(size_t)(b * 8 + cc) * Dc + t];
    hm[t] = s * (1.0f / Nc);
  }
  __syncthreads();
  {
    const float* row = w_in + (size_t)t * Dc;  // Wq row t
    float acc = b_in[t];
    for (int d = 0; d < Dc; ++d) acc += row[d] * hm[d];
    qsh[t] = acc;
  }
  __syncthreads();
  for (int h = 0; h < Hc; ++h) {
    float acc = 0.f;
    const float* wk = w_in + (size_t)(Dc + h * DHc) * Dc + t;  // Wk rows, col t
    const float* qh = qsh + h * DHc;
    #pragma unroll 8
    for (int i = 0; i < DHc; ++i) acc += qh[i] * wk[(size_t)i * Dc];
    g[((size_t)b * Hc + h) * Dc + t] = acc;
  }
  if (t < Hc) {
    float acc = 0.f;
    for (int i = 0; i < DHc; ++i) acc += qsh[t * DHc + i] * b_in[Dc + t * DHc + i];
    c[b * Hc + t] = acc;
  }
}

// ---- setup: M1 = sha_wq @ out_w ; m1b = sha_wq @ out_b ----
__global__ __launch_bounds__(256) void k_A1(const float* __restrict__ swq,
                                            const float* __restrict__ ow,
                                            const float* __restrict__ ob,
                                            float* __restrict__ M1, float* __restrict__ m1b) {
  int i = blockIdx.x, e = threadIdx.x;
  __shared__ float row[Dc];
  __shared__ float red[256];
  row[e] = swq[(size_t)i * Dc + e];
  __syncthreads();
  float acc = 0.f;
  #pragma unroll 4
  for (int k = 0; k < Dc; ++k) acc += row[k] * ow[(size_t)k * Dc + e];
  M1[(size_t)i * Dc + e] = acc;
  red[e] = row[e] * ob[e];
  __syncthreads();
  for (int off = 128; off >= 1; off >>= 1) {
    if (e < off) red[e] += red[e + off];
    __syncthreads();
  }
  if (e == 0) m1b[i] = red[0];
}

// ---- setup: A = sha_wk^T @ M1 ; cvec = A@bv + sha_wk^T@m1b ----
__global__ __launch_bounds__(256) void k_A2(const float* __restrict__ swk,
                                            const float* __restrict__ M1,
                                            const float* __restrict__ m1b,
                                            const float* __restrict__ b_in,
                                            float* __restrict__ Aout, float* __restrict__ cvec) {
  int d = blockIdx.x, e = threadIdx.x;
  __shared__ float col[Dc];
  __shared__ float red[256];
  col[e] = swk[(size_t)e * Dc + d];
  __syncthreads();
  float acc = 0.f;
  #pragma unroll 4
  for (int k = 0; k < Dc; ++k) acc += col[k] * M1[(size_t)k * Dc + e];
  Aout[(size_t)d * Dc + e] = acc;
  red[e] = acc * b_in[2 * Dc + e] + col[e] * m1b[e];
  __syncthreads();
  for (int off = 128; off >= 1; off >>= 1) {
    if (e < off) red[e] += red[e + off];
    __syncthreads();
  }
  if (e == 0) cvec[d] = red[0];
}

// ---- setup: BT[(h*256+e)*256+d] = sum_i A[d][h*32+i] * Wv[h*32+i][e] ----
__global__ __launch_bounds__(256) void k_A3(const float* __restrict__ Aout,
                                            const float* __restrict__ w_in,
                                            float* __restrict__ BT) {
  int h = blockIdx.x >> 3, et = blockIdx.x & 7, d = threadIdx.x;
  float arow[DHc];
  #pragma unroll
  for (int i = 0; i < DHc; ++i) arow[i] = Aout[(size_t)d * Dc + h * DHc + i];
  __shared__ float wv[DHc][DHc];
  for (int k = threadIdx.x; k < DHc * DHc; k += 256) {
    int i = k >> 5, j = k & 31;
    wv[i][j] = w_in[(size_t)(2 * Dc + h * DHc + i) * Dc + et * DHc + j];
  }
  __syncthreads();
  for (int j = 0; j < DHc; ++j) {
    float acc = 0.f;
    #pragma unroll
    for (int i = 0; i < DHc; ++i) acc += arow[i] * wv[i][j];
    BT[((size_t)h * Dc + et * DHc + j) * Dc + d] = acc;
  }
}

// ---- scores: 2 threads per row, 1024 blocks ----
__global__ __launch_bounds__(256) void k_scores(const float* __restrict__ enc,
                                                const float* __restrict__ g,
                                                const float* __restrict__ c,
                                                float* __restrict__ s) {
  int b = blockIdx.x >> 4, nt = blockIdx.x & 15, t = threadIdx.x;
  __shared__ __align__(16) float gsm[Hc * Dc];
  __shared__ float csm[Hc];
  for (int k = t; k < Hc * Dc; k += 256) gsm[k] = g[(size_t)b * Hc * Dc + k];
  if (t < Hc) csm[t] = c[b * Hc + t];
  __syncthreads();
  int row = t >> 1, half = t & 1;
  int n = nt * 128 + row;
  const float4* rowp = reinterpret_cast<const float4*>(enc + ((size_t)b * Nc + n) * Dc);
  float acc[Hc] = {};
  #pragma unroll 8
  for (int i = 0; i < 32; ++i) {
    int d4 = i * 2 + half;
    const float4 e = rowp[d4];
    #pragma unroll
    for (int h = 0; h < Hc; ++h) {
      const float4 g4 = *reinterpret_cast<const float4*>(gsm + h * Dc + d4 * 4);
      acc[h] += e.x * g4.x + e.y * g4.y + e.z * g4.z + e.w * g4.w;
    }
  }
  #pragma unroll
  for (int h = 0; h < Hc; ++h) acc[h] += __shfl_xor(acc[h], 1);
  if (half == 0) {
    #pragma unroll
    for (int h = 0; h < Hc; ++h)
      s[((size_t)b * Hc + h) * Nc + n] = kScale * (acc[h] + csm[h]);
  }
}

// ---- rowmax per (b,h) ----
__global__ __launch_bounds__(256) void k_rowmax(const float* __restrict__ s,
                                                float* __restrict__ mrow) {
  int bh = blockIdx.x, t = threadIdx.x;
  __shared__ float red[256];
  float m = -3.0e38f;
  #pragma unroll
  for (int q = 0; q < 8; ++q) m = fmaxf(m, s[(size_t)bh * Nc + q * 256 + t]);
  red[t] = m;
  __syncthreads();
  for (int off = 128; off >= 1; off >>= 1) {
    if (t < off) red[t] = fmaxf(red[t], red[t + off]);
    __syncthreads();
  }
  if (t == 0) mrow[bh] = red[0];
}

// ---- S0 partials, 8 chunks of 256 rows, float4 loads + transposed weights ----
__global__ __launch_bounds__(256) void k_S0part(const float* __restrict__ enc,
                                                const float* __restrict__ s,
                                                const float* __restrict__ mrow,
                                                float* __restrict__ w,
                                                float* __restrict__ Spart) {
  int b = blockIdx.x >> 3, cid = blockIdx.x & 7, t = threadIdx.x;
  __shared__ __align__(16) float wsmT[256 * 8];       // [row][h]
  __shared__ __align__(16) float part[4][Hc][Dc];     // 32 KB
  {
    float eh[8];
    #pragma unroll
    for (int h = 0; h < Hc; ++h) {
      float m = mrow[b * Hc + h];
      float e = expf(s[((size_t)b * Hc + h) * Nc + cid * 256 + t] - m);
      eh[h] = e;
      w[((size_t)b * Hc + h) * Nc + cid * 256 + t] = e;
    }
    float4 v0; v0.x = eh[0]; v0.y = eh[1]; v0.z = eh[2]; v0.w = eh[3];
    float4 v1; v1.x = eh[4]; v1.y = eh[5]; v1.z = eh[6]; v1.w = eh[7];
    *reinterpret_cast<float4*>(&wsmT[t * 8]) = v0;
    *reinterpret_cast<float4*>(&wsmT[t * 8 + 4]) = v1;
  }
  __syncthreads();
  int lane = t & 63, wv = t >> 6;
  float4 acc[Hc];
  #pragma unroll
  for (int h = 0; h < Hc; ++h) { acc[h].x = 0.f; acc[h].y = 0.f; acc[h].z = 0.f; acc[h].w = 0.f; }
  const float4* ep = reinterpret_cast<const float4*>(
      enc + ((size_t)b * Nc + cid * 256 + wv * 64) * Dc) + lane;
  for (int i = 0; i < 64; ++i) {
    const float4 e4 = ep[(size_t)i * 64];
    int row = wv * 64 + i;
    const float4 w0 = *reinterpret_cast<const float4*>(&wsmT[row * 8]);
    const float4 w1 = *reinterpret_cast<const float4*>(&wsmT[row * 8 + 4]);
    const float wh[8] = {w0.x, w0.y, w0.z, w0.w, w1.x, w1.y, w1.z, w1.w};
    #pragma unroll
    for (int h = 0; h < Hc; ++h) {
      acc[h].x += wh[h] * e4.x; acc[h].y += wh[h] * e4.y;
      acc[h].z += wh[h] * e4.z; acc[h].w += wh[h] * e4.w;
    }
  }
  #pragma unroll
  for (int h = 0; h < Hc; ++h)
    *reinterpret_cast<float4*>(&part[wv][h][lane * 4]) = acc[h];
  __syncthreads();
  #pragma unroll
  for (int h = 0; h < Hc; ++h)
    Spart[(((size_t)b * 8 + cid) * Hc + h) * Dc + t] =
        part[0][h][t] + part[1][h][t] + part[2][h][t] + part[3][h][t];
}

// ---- S0 reduce + W0 = sum_n w ----
__global__ __launch_bounds__(256) void k_S0red(const float* __restrict__ Spart,
                                               const float* __restrict__ w,
                                               float* __restrict__ Sacc,
                                               float* __restrict__ W0) {
  int b = blockIdx.x >> 3, h = blockIdx.x & 7, t = threadIdx.x;
  __shared__ float red[256];
  float acc = 0.f;
  for (int cid = 0; cid < 8; ++cid)
    acc += Spart[(((size_t)b * 8 + cid) * Hc + h) * Dc + t];
  Sacc[((size_t)b * Hc + h) * Dc + t] = acc;
  float ws = 0.f;
  #pragma unroll
  for (int q = 0; q < 8; ++q) ws += w[((size_t)b * Hc + h) * Nc + q * 256 + t];
  red[t] = ws;
  __syncthreads();
  for (int off = 128; off >= 1; off >>= 1) {
    if (t < off) red[t] += red[t + off];
    __syncthreads();
  }
  if (t == 0) W0[b * Hc + h] = red[0];
}

// ---- shared select core: masked log-softmax + argmax + entropy ----
__device__ __forceinline__ void select_core(const float* __restrict__ ub,
                                            const int* histsh, int nhist, int t,
                                            float* red, int* redi,
                                            int& gidx_out, float& lse_out, float& ent_out) {
  float uval[8];
  float lmax = -3.0e38f;
  int lidx = 0;
  #pragma unroll
  for (int q = 0; q < 8; ++q) {
    int n = t + q * 256;
    float v = ub[n];
    for (int tt = 0; tt < nhist; ++tt)
      if (n == histsh[tt]) v = kNeg;
    uval[q] = v;
    if (v > lmax) { lmax = v; lidx = n; }
  }
  red[t] = lmax; redi[t] = lidx;
  __syncthreads();
  for (int off = 128; off >= 1; off >>= 1) {
    if (t < off) {
      float o = red[t + off]; int oi = redi[t + off];
      if (o > red[t] || (o == red[t] && oi < redi[t])) { red[t] = o; redi[t] = oi; }
    }
    __syncthreads();
  }
  float mu = red[0];
  int gidx = redi[0];
  __syncthreads();
  float ssum = 0.f;
  #pragma unroll
  for (int q = 0; q < 8; ++q) ssum += expf(uval[q] - mu);
  red[t] = ssum;
  __syncthreads();
  for (int off = 128; off >= 1; off >>= 1) {
    if (t < off) red[t] += red[t + off];
    __syncthreads();
  }
  float Z = red[0];
  float lse = mu + logf(Z);
  __syncthreads();
  float ent = 0.f;
  #pragma unroll
  for (int q = 0; q < 8; ++q) {
    float logp = uval[q] - lse;
    float p = expf(logp);
    if (p > 0.f) ent -= p * logp;
  }
  red[t] = ent;
  __syncthreads();
  for (int off = 128; off >= 1; off >>= 1) {
    if (t < off) red[t] += red[t + off];
    __syncthreads();
  }
  ent_out = red[0];
  gidx_out = gidx;
  lse_out = lse;
  __syncthreads();  // red/redi safe for reuse
}

// ---- fused select(t-1) + chain(t): block per (b,h), select redundant ----
__global__ __launch_bounds__(256) void k_selchain(const float* __restrict__ u,
                                                  int* __restrict__ hist,
                                                  float* __restrict__ out,
                                                  const float* __restrict__ Sacc,
                                                  const float* __restrict__ W0,
                                                  const float* __restrict__ w,
                                                  const float* __restrict__ enc,
                                                  const float* __restrict__ BT,
                                                  float* __restrict__ rpart, int tstep) {
  int b = blockIdx.x >> 3, h = blockIdx.x & 7, t = threadIdx.x;
  __shared__ float red[256];
  __shared__ int redi[256];
  __shared__ int histsh[16];
  __shared__ float sh[Dc];
  if (t < 16) histsh[t] = (t < tstep - 1) ? hist[b * 16 + t] : -1;
  __syncthreads();

  if (tstep > 0) {
    int sel_t = tstep - 1;
    int gidx; float lse, ent;
    select_core(u + (size_t)b * Nc, histsh, sel_t, t, red, redi, gidx, lse, ent);
    if (h == 0 && t == 0) {
      float pi = expf(u[(size_t)b * Nc + gidx] - lse);
      out[b * Sc + sel_t] = (float)gidx;
      out[Bc * Sc + b * Sc + sel_t] = pi;
      if (sel_t == 0) out[2 * Bc * Sc + b] = ent;
      else out[2 * Bc * Sc + b] += ent;
      hist[b * 16 + sel_t] = gidx;
    }
    if (t == 0) histsh[sel_t] = gidx;
    __syncthreads();
  }

  // chain for own head
  float se = Sacc[((size_t)b * Hc + h) * Dc + t];
  float Wh = W0[b * Hc + h];
  for (int tt = 0; tt < tstep; ++tt) {
    int j = histsh[tt];
    float wv = w[((size_t)b * Hc + h) * Nc + j];
    se -= wv * enc[((size_t)b * Nc + j) * Dc + t];
    Wh -= wv;
  }
  sh[t] = se / Wh;
  __syncthreads();
  const float* bt = BT + (size_t)h * Dc * Dc + t;
  float a0 = 0.f, a1 = 0.f, a2 = 0.f, a3 = 0.f;
  #pragma unroll 4
  for (int e = 0; e < Dc; e += 4) {
    a0 += bt[(size_t)e * Dc] * sh[e];
    a1 += bt[(size_t)(e + 1) * Dc] * sh[e + 1];
    a2 += bt[(size_t)(e + 2) * Dc] * sh[e + 2];
    a3 += bt[(size_t)(e + 3) * Dc] * sh[e + 3];
  }
  rpart[((size_t)b * Hc + h) * Dc + t] = (a0 + a1) + (a2 + a3);
}

// ---- u scores: 4 threads per row, 2048 blocks ----
__global__ __launch_bounds__(256) void k_uscore(const float* __restrict__ enc,
                                                const float* __restrict__ rpart,
                                                const float* __restrict__ cvec,
                                                float* __restrict__ u) {
  int b = blockIdx.x >> 5, ng = blockIdx.x & 31, t = threadIdx.x;
  __shared__ __align__(16) float rsm[Dc];
  {
    float vsum = cvec[t];
    #pragma unroll
    for (int h = 0; h < Hc; ++h) vsum += rpart[((size_t)b * Hc + h) * Dc + t];
    rsm[t] = vsum;
  }
  __syncthreads();
  int row = t >> 2, q = t & 3;
  int n = ng * 64 + row;
  const float4* rowp = reinterpret_cast<const float4*>(enc + ((size_t)b * Nc + n) * Dc);
  const float4* r4 = reinterpret_cast<const float4*>(rsm);
  float acc = 0.f;
  #pragma unroll
  for (int i = 0; i < 16; ++i) {
    int d4 = i * 4 + q;
    const float4 e = rowp[d4];
    const float4 rr = r4[d4];
    acc += e.x * rr.x + e.y * rr.y + e.z * rr.z + e.w * rr.w;
  }
  acc += __shfl_xor(acc, 1);
  acc += __shfl_xor(acc, 2);
  if (q == 0) u[(size_t)b * Nc + n] = kClip * tanhf(kScale2 * acc);
}

// ---- final select (step Sc-1) ----
__global__ __launch_bounds__(256) void k_selfinal(const float* __restrict__ u,
                                                  const int* __restrict__ hist,
                                                  float* __restrict__ out) {
  int b = blockIdx.x, t = threadIdx.x;
  __shared__ float red[256];
  __shared__ int redi[256];
  __shared__ int histsh[16];
  if (t < 16) histsh[t] = (t < Sc - 1) ? hist[b * 16 + t] : -1;
  __syncthreads();
  int gidx; float lse, ent;
  select_core(u + (size_t)b * Nc, histsh, Sc - 1, t, red, redi, gidx, lse, ent);
  if (t == 0) {
    float pi = expf(u[(size_t)b * Nc + gidx] - lse);
    out[b * Sc + (Sc - 1)] = (float)gidx;
    out[Bc * Sc + b * Sc + (Sc - 1)] = pi;
    out[2 * Bc * Sc + b] += ent;
  }
}

extern "C" void kernel_launch(void* const* d_in, const int* in_sizes, int n_in,
                              void* d_out, int out_size, void* d_ws, size_t ws_size,
                              hipStream_t stream) {
  (void)in_sizes; (void)n_in; (void)out_size; (void)ws_size;
  const float* enc  = (const float*)d_in[0];
  const float* in_w = (const float*)d_in[1];
  const float* in_b = (const float*)d_in[2];
  const float* ow   = (const float*)d_in[3];
  const float* ob   = (const float*)d_in[4];
  const float* swq  = (const float*)d_in[5];
  const float* swk  = (const float*)d_in[6];
  float* out = (float*)d_out;

  float* ws = (float*)d_ws;
  size_t off = 0;
  auto alloc = [&](size_t n) { float* p = ws + off; off += n; return p; };
  float* hpart = alloc((size_t)Bc * 8 * Dc);
  float* g     = alloc((size_t)Bc * Hc * Dc);
  float* c     = alloc((size_t)Bc * Hc);
  float* s     = alloc((size_t)Bc * Hc * Nc);
  float* mrow  = alloc((size_t)Bc * Hc);
  float* w     = alloc((size_t)Bc * Hc * Nc);
  float* W0    = alloc((size_t)Bc * Hc);
  float* Spart = alloc((size_t)Bc * 8 * Hc * Dc);
  float* Sacc  = alloc((size_t)Bc * Hc * Dc);
  float* M1    = alloc((size_t)Dc * Dc);
  float* m1b   = alloc(Dc);
  float* Aout  = alloc((size_t)Dc * Dc);
  float* cvec  = alloc(Dc);
  float* BT    = alloc((size_t)Hc * Dc * Dc);
  float* rpart = alloc((size_t)Bc * Hc * Dc);
  float* u     = alloc((size_t)Bc * Nc);
  int* hist    = (int*)alloc((size_t)Bc * 16);

  k_hmean_part<<<Bc * 8, 256, 0, stream>>>(enc, hpart);
  k_qgc<<<Bc, 256, 0, stream>>>(hpart, in_w, in_b, g, c);
  k_A1<<<Dc, 256, 0, stream>>>(swq, ow, ob, M1, m1b);
  k_A2<<<Dc, 256, 0, stream>>>(swk, M1, m1b, in_b, Aout, cvec);
  k_A3<<<Hc * 8, 256, 0, stream>>>(Aout, in_w, BT);
  k_scores<<<Bc * 16, 256, 0, stream>>>(enc, g, c, s);
  k_rowmax<<<Bc * Hc, 256, 0, stream>>>(s, mrow);
  k_S0part<<<Bc * 8, 256, 0, stream>>>(enc, s, mrow, w, Spart);
  k_S0red<<<Bc * Hc, 256, 0, stream>>>(Spart, w, Sacc, W0);

  for (int t = 0; t < Sc; ++t) {
    k_selchain<<<Bc * Hc, 256, 0, stream>>>(u, hist, out, Sacc, W0, w, enc, BT, rpart, t);
    k_uscore<<<Bc * 32, 256, 0, stream>>>(enc, rpart, cvec, u);
  }
  k_selfinal<<<Bc, 256, 0, stream>>>(u, hist, out);
}

// Round 12
// 506.896 us; speedup vs baseline: 5.6652x; 1.0035x over previous
//
#include <hip/hip_runtime.h>
#include <hip/hip_bf16.h>
#include <math.h>

namespace {
constexpr int Bc = 64, Nc = 2048, Dc = 256, Hc = 8, DHc = 32, Sc = 10;
constexpr float kNeg = -1000000000.0f;
constexpr float kClip = 10.0f;
constexpr float kScale = 0.17677669529663687f;   // 1/sqrt(32)
constexpr float kScale2 = 0.0625f;               // 1/sqrt(256)
}

// ---- h_mean partials: 512 blocks, 256-row chunks, float4 loads ----
__global__ __launch_bounds__(256) void k_hmean_part(const float* __restrict__ enc,
                                                    float* __restrict__ hpart) {
  int b = blockIdx.x >> 3, c = blockIdx.x & 7, t = threadIdx.x;
  int lane = t & 63, wv = t >> 6;
  __shared__ __align__(16) float part[4][Dc];
  const float4* p = reinterpret_cast<const float4*>(
      enc + ((size_t)b * Nc + c * 256 + wv * 64) * Dc) + lane;
  float4 s; s.x = 0.f; s.y = 0.f; s.z = 0.f; s.w = 0.f;
  #pragma unroll 8
  for (int i = 0; i < 64; ++i) {
    const float4 e = p[(size_t)i * 64];
    s.x += e.x; s.y += e.y; s.z += e.z; s.w += e.w;
  }
  *reinterpret_cast<float4*>(&part[wv][lane * 4]) = s;
  __syncthreads();
  hpart[(size_t)blockIdx.x * Dc + t] =
      part[0][t] + part[1][t] + part[2][t] + part[3][t];
}

// ---- qgc (folds hmean reduction): q, g, c ----
__global__ __launch_bounds__(256) void k_qgc(const float* __restrict__ hpart,
                                             const float* __restrict__ w_in,
                                             const float* __restrict__ b_in,
                                             float* __restrict__ g, float* __restrict__ c) {
  int b = blockIdx.x, t = threadIdx.x;
  __shared__ float hm[Dc];
  __shared__ float qsh[Dc];
  {
    float s = 0.f;
    for (int cc = 0; cc < 8; ++cc) s += hpart[(size_t)(b * 8 + cc) * Dc + t];
    hm[t] = s * (1.0f / Nc);
  }
  __syncthreads();
  {
    const float* row = w_in + (size_t)t * Dc;  // Wq row t
    float acc = b_in[t];
    for (int d = 0; d < Dc; ++d) acc += row[d] * hm[d];
    qsh[t] = acc;
  }
  __syncthreads();
  for (int h = 0; h < Hc; ++h) {
    float acc = 0.f;
    const float* wk = w_in + (size_t)(Dc + h * DHc) * Dc + t;  // Wk rows, col t
    const float* qh = qsh + h * DHc;
    #pragma unroll 8
    for (int i = 0; i < DHc; ++i) acc += qh[i] * wk[(size_t)i * Dc];
    g[((size_t)b * Hc + h) * Dc + t] = acc;
  }
  if (t < Hc) {
    float acc = 0.f;
    for (int i = 0; i < DHc; ++i) acc += qsh[t * DHc + i] * b_in[Dc + t * DHc + i];
    c[b * Hc + t] = acc;
  }
}

// ---- setup: M1 = sha_wq @ out_w ; m1b = sha_wq @ out_b ----
__global__ __launch_bounds__(256) void k_A1(const float* __restrict__ swq,
                                            const float* __restrict__ ow,
                                            const float* __restrict__ ob,
                                            float* __restrict__ M1, float* __restrict__ m1b) {
  int i = blockIdx.x, e = threadIdx.x;
  __shared__ float row[Dc];
  __shared__ float red[256];
  row[e] = swq[(size_t)i * Dc + e];
  __syncthreads();
  float acc = 0.f;
  #pragma unroll 4
  for (int k = 0; k < Dc; ++k) acc += row[k] * ow[(size_t)k * Dc + e];
  M1[(size_t)i * Dc + e] = acc;
  red[e] = row[e] * ob[e];
  __syncthreads();
  for (int off = 128; off >= 1; off >>= 1) {
    if (e < off) red[e] += red[e + off];
    __syncthreads();
  }
  if (e == 0) m1b[i] = red[0];
}

// ---- setup: A = sha_wk^T @ M1 ; cvec = A@bv + sha_wk^T@m1b ----
__global__ __launch_bounds__(256) void k_A2(const float* __restrict__ swk,
                                            const float* __restrict__ M1,
                                            const float* __restrict__ m1b,
                                            const float* __restrict__ b_in,
                                            float* __restrict__ Aout, float* __restrict__ cvec) {
  int d = blockIdx.x, e = threadIdx.x;
  __shared__ float col[Dc];
  __shared__ float red[256];
  col[e] = swk[(size_t)e * Dc + d];
  __syncthreads();
  float acc = 0.f;
  #pragma unroll 4
  for (int k = 0; k < Dc; ++k) acc += col[k] * M1[(size_t)k * Dc + e];
  Aout[(size_t)d * Dc + e] = acc;
  red[e] = acc * b_in[2 * Dc + e] + col[e] * m1b[e];
  __syncthreads();
  for (int off = 128; off >= 1; off >>= 1) {
    if (e < off) red[e] += red[e + off];
    __syncthreads();
  }
  if (e == 0) cvec[d] = red[0];
}

// ---- setup: BT[(h*256+e)*256+d] = sum_i A[d][h*32+i] * Wv[h*32+i][e] ----
__global__ __launch_bounds__(256) void k_A3(const float* __restrict__ Aout,
                                            const float* __restrict__ w_in,
                                            float* __restrict__ BT) {
  int h = blockIdx.x >> 3, et = blockIdx.x & 7, d = threadIdx.x;
  float arow[DHc];
  #pragma unroll
  for (int i = 0; i < DHc; ++i) arow[i] = Aout[(size_t)d * Dc + h * DHc + i];
  __shared__ float wv[DHc][DHc];
  for (int k = threadIdx.x; k < DHc * DHc; k += 256) {
    int i = k >> 5, j = k & 31;
    wv[i][j] = w_in[(size_t)(2 * Dc + h * DHc + i) * Dc + et * DHc + j];
  }
  __syncthreads();
  for (int j = 0; j < DHc; ++j) {
    float acc = 0.f;
    #pragma unroll
    for (int i = 0; i < DHc; ++i) acc += arow[i] * wv[i][j];
    BT[((size_t)h * Dc + et * DHc + j) * Dc + d] = acc;
  }
}

// ---- fused scores + chunk-local softmax + S0 partials: 512 blocks ----
// Phase 1 (thread=row): 8 head scores in regs, wave+LDS chunk max, w_raw = exp(s-mc).
// Phase 2 (thread=d): Spart accumulation (enc slice re-read, L2-hot).
__global__ __launch_bounds__(256) void k_scoreS0(const float* __restrict__ enc,
                                                 const float* __restrict__ g,
                                                 const float* __restrict__ c,
                                                 float* __restrict__ w,
                                                 float* __restrict__ Spart,
                                                 float* __restrict__ mrowc) {
  int b = blockIdx.x >> 3, cid = blockIdx.x & 7, t = threadIdx.x;
  int lane = t & 63, wvi = t >> 6;
  __shared__ __align__(16) float gsm[Hc * Dc];
  __shared__ float csm[Hc];
  __shared__ __align__(16) float wsmT[256 * 8];       // [row][h]
  __shared__ __align__(16) float part[4][Hc][Dc];     // 32 KB
  __shared__ float wmax[4][Hc];
  for (int k = t; k < Hc * Dc; k += 256) gsm[k] = g[(size_t)b * Hc * Dc + k];
  if (t < Hc) csm[t] = c[b * Hc + t];
  __syncthreads();

  // phase 1: thread t = row within chunk
  int n = cid * 256 + t;
  float sv[Hc];
  {
    const float4* rowp = reinterpret_cast<const float4*>(enc + ((size_t)b * Nc + n) * Dc);
    float acc[Hc] = {};
    #pragma unroll 8
    for (int d4 = 0; d4 < 64; ++d4) {
      const float4 e = rowp[d4];
      #pragma unroll
      for (int h = 0; h < Hc; ++h) {
        const float4 g4 = *reinterpret_cast<const float4*>(gsm + h * Dc + d4 * 4);
        acc[h] += e.x * g4.x + e.y * g4.y + e.z * g4.z + e.w * g4.w;
      }
    }
    #pragma unroll
    for (int h = 0; h < Hc; ++h) sv[h] = kScale * (acc[h] + csm[h]);
  }
  // chunk max per h: wave shfl reduce + cross-wave LDS combine
  {
    float wm[Hc];
    #pragma unroll
    for (int h = 0; h < Hc; ++h) {
      float m = sv[h];
      #pragma unroll
      for (int off = 32; off >= 1; off >>= 1) m = fmaxf(m, __shfl_xor(m, off));
      wm[h] = m;
    }
    if (lane == 0) {
      #pragma unroll
      for (int h = 0; h < Hc; ++h) wmax[wvi][h] = wm[h];
    }
  }
  __syncthreads();
  {
    float eh[Hc];
    #pragma unroll
    for (int h = 0; h < Hc; ++h) {
      float mc = fmaxf(fmaxf(wmax[0][h], wmax[1][h]), fmaxf(wmax[2][h], wmax[3][h]));
      float e = expf(sv[h] - mc);
      eh[h] = e;
      w[((size_t)b * Hc + h) * Nc + n] = e;    // chunk-scaled; S0red rescales
      if (t == 0) mrowc[((size_t)b * 8 + cid) * Hc + h] = mc;
    }
    float4 v0; v0.x = eh[0]; v0.y = eh[1]; v0.z = eh[2]; v0.w = eh[3];
    float4 v1; v1.x = eh[4]; v1.y = eh[5]; v1.z = eh[6]; v1.w = eh[7];
    *reinterpret_cast<float4*>(&wsmT[t * 8]) = v0;
    *reinterpret_cast<float4*>(&wsmT[t * 8 + 4]) = v1;
  }
  __syncthreads();

  // phase 2: wave-split S0 accumulation (enc slice from L2)
  float4 acc2[Hc];
  #pragma unroll
  for (int h = 0; h < Hc; ++h) { acc2[h].x = 0.f; acc2[h].y = 0.f; acc2[h].z = 0.f; acc2[h].w = 0.f; }
  const float4* ep = reinterpret_cast<const float4*>(
      enc + ((size_t)b * Nc + cid * 256 + wvi * 64) * Dc) + lane;
  for (int i = 0; i < 64; ++i) {
    const float4 e4 = ep[(size_t)i * 64];
    int row = wvi * 64 + i;
    const float4 w0 = *reinterpret_cast<const float4*>(&wsmT[row * 8]);
    const float4 w1 = *reinterpret_cast<const float4*>(&wsmT[row * 8 + 4]);
    const float wh[8] = {w0.x, w0.y, w0.z, w0.w, w1.x, w1.y, w1.z, w1.w};
    #pragma unroll
    for (int h = 0; h < Hc; ++h) {
      acc2[h].x += wh[h] * e4.x; acc2[h].y += wh[h] * e4.y;
      acc2[h].z += wh[h] * e4.z; acc2[h].w += wh[h] * e4.w;
    }
  }
  #pragma unroll
  for (int h = 0; h < Hc; ++h)
    *reinterpret_cast<float4*>(&part[wvi][h][lane * 4]) = acc2[h];
  __syncthreads();
  #pragma unroll
  for (int h = 0; h < Hc; ++h)
    Spart[(((size_t)b * 8 + cid) * Hc + h) * Dc + t] =
        part[0][h][t] + part[1][h][t] + part[2][h][t] + part[3][h][t];
}

// ---- S0 reduce with chunk-factor rescale + w correction + W0 ----
__global__ __launch_bounds__(256) void k_S0red(const float* __restrict__ Spart,
                                               const float* __restrict__ mrowc,
                                               float* __restrict__ w,
                                               float* __restrict__ Sacc,
                                               float* __restrict__ W0) {
  int b = blockIdx.x >> 3, h = blockIdx.x & 7, t = threadIdx.x;
  __shared__ float red[256];
  float mc[8], m = -3.0e38f;
  #pragma unroll
  for (int cd = 0; cd < 8; ++cd) {
    mc[cd] = mrowc[((size_t)b * 8 + cd) * Hc + h];
    m = fmaxf(m, mc[cd]);
  }
  float f[8];
  #pragma unroll
  for (int cd = 0; cd < 8; ++cd) f[cd] = expf(mc[cd] - m);
  float acc = 0.f;
  #pragma unroll
  for (int cd = 0; cd < 8; ++cd)
    acc += Spart[(((size_t)b * 8 + cd) * Hc + h) * Dc + t] * f[cd];
  Sacc[((size_t)b * Hc + h) * Dc + t] = acc;
  float ws = 0.f;
  #pragma unroll
  for (int q = 0; q < 8; ++q) {
    size_t idx = ((size_t)b * Hc + h) * Nc + q * 256 + t;
    float v = w[idx] * f[q];      // chunk q holds rows q*256..q*256+255
    w[idx] = v;
    ws += v;
  }
  red[t] = ws;
  __syncthreads();
  for (int off = 128; off >= 1; off >>= 1) {
    if (t < off) red[t] += red[t + off];
    __syncthreads();
  }
  if (t == 0) W0[b * Hc + h] = red[0];
}

// ---- shared select core: masked log-softmax + argmax + entropy ----
__device__ __forceinline__ void select_core(const float* __restrict__ ub,
                                            const int* histsh, int nhist, int t,
                                            float* red, int* redi,
                                            int& gidx_out, float& lse_out, float& ent_out) {
  float uval[8];
  float lmax = -3.0e38f;
  int lidx = 0;
  #pragma unroll
  for (int q = 0; q < 8; ++q) {
    int n = t + q * 256;
    float v = ub[n];
    for (int tt = 0; tt < nhist; ++tt)
      if (n == histsh[tt]) v = kNeg;
    uval[q] = v;
    if (v > lmax) { lmax = v; lidx = n; }
  }
  red[t] = lmax; redi[t] = lidx;
  __syncthreads();
  for (int off = 128; off >= 1; off >>= 1) {
    if (t < off) {
      float o = red[t + off]; int oi = redi[t + off];
      if (o > red[t] || (o == red[t] && oi < redi[t])) { red[t] = o; redi[t] = oi; }
    }
    __syncthreads();
  }
  float mu = red[0];
  int gidx = redi[0];
  __syncthreads();
  float ssum = 0.f;
  #pragma unroll
  for (int q = 0; q < 8; ++q) ssum += expf(uval[q] - mu);
  red[t] = ssum;
  __syncthreads();
  for (int off = 128; off >= 1; off >>= 1) {
    if (t < off) red[t] += red[t + off];
    __syncthreads();
  }
  float Z = red[0];
  float lse = mu + logf(Z);
  __syncthreads();
  float ent = 0.f;
  #pragma unroll
  for (int q = 0; q < 8; ++q) {
    float logp = uval[q] - lse;
    float p = expf(logp);
    if (p > 0.f) ent -= p * logp;
  }
  red[t] = ent;
  __syncthreads();
  for (int off = 128; off >= 1; off >>= 1) {
    if (t < off) red[t] += red[t + off];
    __syncthreads();
  }
  ent_out = red[0];
  gidx_out = gidx;
  lse_out = lse;
  __syncthreads();  // red/redi safe for reuse
}

// ---- fused select(t-1) + chain(t): block per (b,h), select redundant ----
__global__ __launch_bounds__(256) void k_selchain(const float* __restrict__ u,
                                                  int* __restrict__ hist,
                                                  float* __restrict__ out,
                                                  const float* __restrict__ Sacc,
                                                  const float* __restrict__ W0,
                                                  const float* __restrict__ w,
                                                  const float* __restrict__ enc,
                                                  const float* __restrict__ BT,
                                                  float* __restrict__ rpart, int tstep) {
  int b = blockIdx.x >> 3, h = blockIdx.x & 7, t = threadIdx.x;
  __shared__ float red[256];
  __shared__ int redi[256];
  __shared__ int histsh[16];
  __shared__ float sh[Dc];
  if (t < 16) histsh[t] = (t < tstep - 1) ? hist[b * 16 + t] : -1;
  __syncthreads();

  if (tstep > 0) {
    int sel_t = tstep - 1;
    int gidx; float lse, ent;
    select_core(u + (size_t)b * Nc, histsh, sel_t, t, red, redi, gidx, lse, ent);
    if (h == 0 && t == 0) {
      float pi = expf(u[(size_t)b * Nc + gidx] - lse);
      out[b * Sc + sel_t] = (float)gidx;
      out[Bc * Sc + b * Sc + sel_t] = pi;
      if (sel_t == 0) out[2 * Bc * Sc + b] = ent;
      else out[2 * Bc * Sc + b] += ent;
      hist[b * 16 + sel_t] = gidx;
    }
    if (t == 0) histsh[sel_t] = gidx;
    __syncthreads();
  }

  // chain for own head
  float se = Sacc[((size_t)b * Hc + h) * Dc + t];
  float Wh = W0[b * Hc + h];
  for (int tt = 0; tt < tstep; ++tt) {
    int j = histsh[tt];
    float wv = w[((size_t)b * Hc + h) * Nc + j];
    se -= wv * enc[((size_t)b * Nc + j) * Dc + t];
    Wh -= wv;
  }
  sh[t] = se / Wh;
  __syncthreads();
  const float* bt = BT + (size_t)h * Dc * Dc + t;
  float a0 = 0.f, a1 = 0.f, a2 = 0.f, a3 = 0.f;
  #pragma unroll 4
  for (int e = 0; e < Dc; e += 4) {
    a0 += bt[(size_t)e * Dc] * sh[e];
    a1 += bt[(size_t)(e + 1) * Dc] * sh[e + 1];
    a2 += bt[(size_t)(e + 2) * Dc] * sh[e + 2];
    a3 += bt[(size_t)(e + 3) * Dc] * sh[e + 3];
  }
  rpart[((size_t)b * Hc + h) * Dc + t] = (a0 + a1) + (a2 + a3);
}

// ---- u scores: 4 threads per row, 2048 blocks ----
__global__ __launch_bounds__(256) void k_uscore(const float* __restrict__ enc,
                                                const float* __restrict__ rpart,
                                                const float* __restrict__ cvec,
                                                float* __restrict__ u) {
  int b = blockIdx.x >> 5, ng = blockIdx.x & 31, t = threadIdx.x;
  __shared__ __align__(16) float rsm[Dc];
  {
    float vsum = cvec[t];
    #pragma unroll
    for (int h = 0; h < Hc; ++h) vsum += rpart[((size_t)b * Hc + h) * Dc + t];
    rsm[t] = vsum;
  }
  __syncthreads();
  int row = t >> 2, q = t & 3;
  int n = ng * 64 + row;
  const float4* rowp = reinterpret_cast<const float4*>(enc + ((size_t)b * Nc + n) * Dc);
  const float4* r4 = reinterpret_cast<const float4*>(rsm);
  float acc = 0.f;
  #pragma unroll
  for (int i = 0; i < 16; ++i) {
    int d4 = i * 4 + q;
    const float4 e = rowp[d4];
    const float4 rr = r4[d4];
    acc += e.x * rr.x + e.y * rr.y + e.z * rr.z + e.w * rr.w;
  }
  acc += __shfl_xor(acc, 1);
  acc += __shfl_xor(acc, 2);
  if (q == 0) u[(size_t)b * Nc + n] = kClip * tanhf(kScale2 * acc);
}

// ---- final select (step Sc-1) ----
__global__ __launch_bounds__(256) void k_selfinal(const float* __restrict__ u,
                                                  const int* __restrict__ hist,
                                                  float* __restrict__ out) {
  int b = blockIdx.x, t = threadIdx.x;
  __shared__ float red[256];
  __shared__ int redi[256];
  __shared__ int histsh[16];
  if (t < 16) histsh[t] = (t < Sc - 1) ? hist[b * 16 + t] : -1;
  __syncthreads();
  int gidx; float lse, ent;
  select_core(u + (size_t)b * Nc, histsh, Sc - 1, t, red, redi, gidx, lse, ent);
  if (t == 0) {
    float pi = expf(u[(size_t)b * Nc + gidx] - lse);
    out[b * Sc + (Sc - 1)] = (float)gidx;
    out[Bc * Sc + b * Sc + (Sc - 1)] = pi;
    out[2 * Bc * Sc + b] += ent;
  }
}

extern "C" void kernel_launch(void* const* d_in, const int* in_sizes, int n_in,
                              void* d_out, int out_size, void* d_ws, size_t ws_size,
                              hipStream_t stream) {
  (void)in_sizes; (void)n_in; (void)out_size; (void)ws_size;
  const float* enc  = (const float*)d_in[0];
  const float* in_w = (const float*)d_in[1];
  const float* in_b = (const float*)d_in[2];
  const float* ow   = (const float*)d_in[3];
  const float* ob   = (const float*)d_in[4];
  const float* swq  = (const float*)d_in[5];
  const float* swk  = (const float*)d_in[6];
  float* out = (float*)d_out;

  float* ws = (float*)d_ws;
  size_t off = 0;
  auto alloc = [&](size_t n) { float* p = ws + off; off += n; return p; };
  float* hpart = alloc((size_t)Bc * 8 * Dc);
  float* g     = alloc((size_t)Bc * Hc * Dc);
  float* c     = alloc((size_t)Bc * Hc);
  float* w     = alloc((size_t)Bc * Hc * Nc);
  float* W0    = alloc((size_t)Bc * Hc);
  float* Spart = alloc((size_t)Bc * 8 * Hc * Dc);
  float* mrowc = alloc((size_t)Bc * 8 * Hc);
  float* Sacc  = alloc((size_t)Bc * Hc * Dc);
  float* M1    = alloc((size_t)Dc * Dc);
  float* m1b   = alloc(Dc);
  float* Aout  = alloc((size_t)Dc * Dc);
  float* cvec  = alloc(Dc);
  float* BT    = alloc((size_t)Hc * Dc * Dc);
  float* rpart = alloc((size_t)Bc * Hc * Dc);
  float* u     = alloc((size_t)Bc * Nc);
  int* hist    = (int*)alloc((size_t)Bc * 16);

  k_hmean_part<<<Bc * 8, 256, 0, stream>>>(enc, hpart);
  k_qgc<<<Bc, 256, 0, stream>>>(hpart, in_w, in_b, g, c);
  k_A1<<<Dc, 256, 0, stream>>>(swq, ow, ob, M1, m1b);
  k_A2<<<Dc, 256, 0, stream>>>(swk, M1, m1b, in_b, Aout, cvec);
  k_A3<<<Hc * 8, 256, 0, stream>>>(Aout, in_w, BT);
  k_scoreS0<<<Bc * 8, 256, 0, stream>>>(enc, g, c, w, Spart, mrowc);
  k_S0red<<<Bc * Hc, 256, 0, stream>>>(Spart, mrowc, w, Sacc, W0);

  for (int t = 0; t < Sc; ++t) {
    k_selchain<<<Bc * Hc, 256, 0, stream>>>(u, hist, out, Sacc, W0, w, enc, BT, rpart, t);
    k_uscore<<<Bc * 32, 256, 0, stream>>>(enc, rpart, cvec, u);
  }
  k_selfinal<<<Bc, 256, 0, stream>>>(u, hist, out);
}

// Round 13
// 495.470 us; speedup vs baseline: 5.7958x; 1.0231x over previous
//
#include <hip/hip_runtime.h>
#include <hip/hip_bf16.h>
#include <math.h>

namespace {
constexpr int Bc = 64, Nc = 2048, Dc = 256, Hc = 8, DHc = 32, Sc = 10;
constexpr float kNeg = -1000000000.0f;
constexpr float kClip = 10.0f;
constexpr float kScale = 0.17677669529663687f;   // 1/sqrt(32)
constexpr float kScale2 = 0.0625f;               // 1/sqrt(256)
}

// ---- h_mean partials: 512 blocks, 256-row chunks, float4 loads ----
__global__ __launch_bounds__(256) void k_hmean_part(const float* __restrict__ enc,
                                                    float* __restrict__ hpart) {
  int b = blockIdx.x >> 3, c = blockIdx.x & 7, t = threadIdx.x;
  int lane = t & 63, wv = t >> 6;
  __shared__ __align__(16) float part[4][Dc];
  const float4* p = reinterpret_cast<const float4*>(
      enc + ((size_t)b * Nc + c * 256 + wv * 64) * Dc) + lane;
  float4 s; s.x = 0.f; s.y = 0.f; s.z = 0.f; s.w = 0.f;
  #pragma unroll 8
  for (int i = 0; i < 64; ++i) {
    const float4 e = p[(size_t)i * 64];
    s.x += e.x; s.y += e.y; s.z += e.z; s.w += e.w;
  }
  *reinterpret_cast<float4*>(&part[wv][lane * 4]) = s;
  __syncthreads();
  hpart[(size_t)blockIdx.x * Dc + t] =
      part[0][t] + part[1][t] + part[2][t] + part[3][t];
}

// ---- qgc (folds hmean reduction): q, g, c ----
__global__ __launch_bounds__(256) void k_qgc(const float* __restrict__ hpart,
                                             const float* __restrict__ w_in,
                                             const float* __restrict__ b_in,
                                             float* __restrict__ g, float* __restrict__ c) {
  int b = blockIdx.x, t = threadIdx.x;
  __shared__ float hm[Dc];
  __shared__ float qsh[Dc];
  {
    float s = 0.f;
    for (int cc = 0; cc < 8; ++cc) s += hpart[(size_t)(b * 8 + cc) * Dc + t];
    hm[t] = s * (1.0f / Nc);
  }
  __syncthreads();
  {
    const float* row = w_in + (size_t)t * Dc;  // Wq row t
    float acc = b_in[t];
    for (int d = 0; d < Dc; ++d) acc += row[d] * hm[d];
    qsh[t] = acc;
  }
  __syncthreads();
  for (int h = 0; h < Hc; ++h) {
    float acc = 0.f;
    const float* wk = w_in + (size_t)(Dc + h * DHc) * Dc + t;  // Wk rows, col t
    const float* qh = qsh + h * DHc;
    #pragma unroll 8
    for (int i = 0; i < DHc; ++i) acc += qh[i] * wk[(size_t)i * Dc];
    g[((size_t)b * Hc + h) * Dc + t] = acc;
  }
  if (t < Hc) {
    float acc = 0.f;
    for (int i = 0; i < DHc; ++i) acc += qsh[t * DHc + i] * b_in[Dc + t * DHc + i];
    c[b * Hc + t] = acc;
  }
}

// ---- setup: M1 = sha_wq @ out_w ; m1b = sha_wq @ out_b ----
__global__ __launch_bounds__(256) void k_A1(const float* __restrict__ swq,
                                            const float* __restrict__ ow,
                                            const float* __restrict__ ob,
                                            float* __restrict__ M1, float* __restrict__ m1b) {
  int i = blockIdx.x, e = threadIdx.x;
  __shared__ float row[Dc];
  __shared__ float red[256];
  row[e] = swq[(size_t)i * Dc + e];
  __syncthreads();
  float acc = 0.f;
  #pragma unroll 4
  for (int k = 0; k < Dc; ++k) acc += row[k] * ow[(size_t)k * Dc + e];
  M1[(size_t)i * Dc + e] = acc;
  red[e] = row[e] * ob[e];
  __syncthreads();
  for (int off = 128; off >= 1; off >>= 1) {
    if (e < off) red[e] += red[e + off];
    __syncthreads();
  }
  if (e == 0) m1b[i] = red[0];
}

// ---- setup: A = sha_wk^T @ M1 ; cvec = A@bv + sha_wk^T@m1b ----
__global__ __launch_bounds__(256) void k_A2(const float* __restrict__ swk,
                                            const float* __restrict__ M1,
                                            const float* __restrict__ m1b,
                                            const float* __restrict__ b_in,
                                            float* __restrict__ Aout, float* __restrict__ cvec) {
  int d = blockIdx.x, e = threadIdx.x;
  __shared__ float col[Dc];
  __shared__ float red[256];
  col[e] = swk[(size_t)e * Dc + d];
  __syncthreads();
  float acc = 0.f;
  #pragma unroll 4
  for (int k = 0; k < Dc; ++k) acc += col[k] * M1[(size_t)k * Dc + e];
  Aout[(size_t)d * Dc + e] = acc;
  red[e] = acc * b_in[2 * Dc + e] + col[e] * m1b[e];
  __syncthreads();
  for (int off = 128; off >= 1; off >>= 1) {
    if (e < off) red[e] += red[e + off];
    __syncthreads();
  }
  if (e == 0) cvec[d] = red[0];
}

// ---- setup: BT[(h*256+e)*256+d] = sum_i A[d][h*32+i] * Wv[h*32+i][e] ----
__global__ __launch_bounds__(256) void k_A3(const float* __restrict__ Aout,
                                            const float* __restrict__ w_in,
                                            float* __restrict__ BT) {
  int h = blockIdx.x >> 3, et = blockIdx.x & 7, d = threadIdx.x;
  float arow[DHc];
  #pragma unroll
  for (int i = 0; i < DHc; ++i) arow[i] = Aout[(size_t)d * Dc + h * DHc + i];
  __shared__ float wv[DHc][DHc];
  for (int k = threadIdx.x; k < DHc * DHc; k += 256) {
    int i = k >> 5, j = k & 31;
    wv[i][j] = w_in[(size_t)(2 * Dc + h * DHc + i) * Dc + et * DHc + j];
  }
  __syncthreads();
  for (int j = 0; j < DHc; ++j) {
    float acc = 0.f;
    #pragma unroll
    for (int i = 0; i < DHc; ++i) acc += arow[i] * wv[i][j];
    BT[((size_t)h * Dc + et * DHc + j) * Dc + d] = acc;
  }
}

// ---- fused scores + chunk-local softmax + S0 partials: 512 blocks ----
__global__ __launch_bounds__(256) void k_scoreS0(const float* __restrict__ enc,
                                                 const float* __restrict__ g,
                                                 const float* __restrict__ c,
                                                 float* __restrict__ w,
                                                 float* __restrict__ Spart,
                                                 float* __restrict__ mrowc) {
  int b = blockIdx.x >> 3, cid = blockIdx.x & 7, t = threadIdx.x;
  int lane = t & 63, wvi = t >> 6;
  __shared__ __align__(16) float gsm[Hc * Dc];
  __shared__ float csm[Hc];
  __shared__ __align__(16) float wsmT[256 * 8];       // [row][h]
  __shared__ __align__(16) float part[4][Hc][Dc];     // 32 KB
  __shared__ float wmax[4][Hc];
  for (int k = t; k < Hc * Dc; k += 256) gsm[k] = g[(size_t)b * Hc * Dc + k];
  if (t < Hc) csm[t] = c[b * Hc + t];
  __syncthreads();

  // phase 1: thread t = row within chunk
  int n = cid * 256 + t;
  float sv[Hc];
  {
    const float4* rowp = reinterpret_cast<const float4*>(enc + ((size_t)b * Nc + n) * Dc);
    float acc[Hc] = {};
    #pragma unroll 8
    for (int d4 = 0; d4 < 64; ++d4) {
      const float4 e = rowp[d4];
      #pragma unroll
      for (int h = 0; h < Hc; ++h) {
        const float4 g4 = *reinterpret_cast<const float4*>(gsm + h * Dc + d4 * 4);
        acc[h] += e.x * g4.x + e.y * g4.y + e.z * g4.z + e.w * g4.w;
      }
    }
    #pragma unroll
    for (int h = 0; h < Hc; ++h) sv[h] = kScale * (acc[h] + csm[h]);
  }
  {
    float wm[Hc];
    #pragma unroll
    for (int h = 0; h < Hc; ++h) {
      float m = sv[h];
      #pragma unroll
      for (int off = 32; off >= 1; off >>= 1) m = fmaxf(m, __shfl_xor(m, off));
      wm[h] = m;
    }
    if (lane == 0) {
      #pragma unroll
      for (int h = 0; h < Hc; ++h) wmax[wvi][h] = wm[h];
    }
  }
  __syncthreads();
  {
    float eh[Hc];
    #pragma unroll
    for (int h = 0; h < Hc; ++h) {
      float mc = fmaxf(fmaxf(wmax[0][h], wmax[1][h]), fmaxf(wmax[2][h], wmax[3][h]));
      float e = expf(sv[h] - mc);
      eh[h] = e;
      w[((size_t)b * Hc + h) * Nc + n] = e;    // chunk-scaled; S0red rescales
      if (t == 0) mrowc[((size_t)b * 8 + cid) * Hc + h] = mc;
    }
    float4 v0; v0.x = eh[0]; v0.y = eh[1]; v0.z = eh[2]; v0.w = eh[3];
    float4 v1; v1.x = eh[4]; v1.y = eh[5]; v1.z = eh[6]; v1.w = eh[7];
    *reinterpret_cast<float4*>(&wsmT[t * 8]) = v0;
    *reinterpret_cast<float4*>(&wsmT[t * 8 + 4]) = v1;
  }
  __syncthreads();

  // phase 2: wave-split S0 accumulation (enc slice from L2)
  float4 acc2[Hc];
  #pragma unroll
  for (int h = 0; h < Hc; ++h) { acc2[h].x = 0.f; acc2[h].y = 0.f; acc2[h].z = 0.f; acc2[h].w = 0.f; }
  const float4* ep = reinterpret_cast<const float4*>(
      enc + ((size_t)b * Nc + cid * 256 + wvi * 64) * Dc) + lane;
  for (int i = 0; i < 64; ++i) {
    const float4 e4 = ep[(size_t)i * 64];
    int row = wvi * 64 + i;
    const float4 w0 = *reinterpret_cast<const float4*>(&wsmT[row * 8]);
    const float4 w1 = *reinterpret_cast<const float4*>(&wsmT[row * 8 + 4]);
    const float wh[8] = {w0.x, w0.y, w0.z, w0.w, w1.x, w1.y, w1.z, w1.w};
    #pragma unroll
    for (int h = 0; h < Hc; ++h) {
      acc2[h].x += wh[h] * e4.x; acc2[h].y += wh[h] * e4.y;
      acc2[h].z += wh[h] * e4.z; acc2[h].w += wh[h] * e4.w;
    }
  }
  #pragma unroll
  for (int h = 0; h < Hc; ++h)
    *reinterpret_cast<float4*>(&part[wvi][h][lane * 4]) = acc2[h];
  __syncthreads();
  #pragma unroll
  for (int h = 0; h < Hc; ++h)
    Spart[(((size_t)b * 8 + cid) * Hc + h) * Dc + t] =
        part[0][h][t] + part[1][h][t] + part[2][h][t] + part[3][h][t];
}

// ---- S0 reduce with chunk-factor rescale + w correction + W0 (shfl) ----
__global__ __launch_bounds__(256) void k_S0red(const float* __restrict__ Spart,
                                               const float* __restrict__ mrowc,
                                               float* __restrict__ w,
                                               float* __restrict__ Sacc,
                                               float* __restrict__ W0) {
  int b = blockIdx.x >> 3, h = blockIdx.x & 7, t = threadIdx.x;
  int lane = t & 63, wv = t >> 6;
  __shared__ float rws[4];
  float mc[8], m = -3.0e38f;
  #pragma unroll
  for (int cd = 0; cd < 8; ++cd) {
    mc[cd] = mrowc[((size_t)b * 8 + cd) * Hc + h];
    m = fmaxf(m, mc[cd]);
  }
  float f[8];
  #pragma unroll
  for (int cd = 0; cd < 8; ++cd) f[cd] = expf(mc[cd] - m);
  float acc = 0.f;
  #pragma unroll
  for (int cd = 0; cd < 8; ++cd)
    acc += Spart[(((size_t)b * 8 + cd) * Hc + h) * Dc + t] * f[cd];
  Sacc[((size_t)b * Hc + h) * Dc + t] = acc;
  float ws = 0.f;
  #pragma unroll
  for (int q = 0; q < 8; ++q) {
    size_t idx = ((size_t)b * Hc + h) * Nc + q * 256 + t;
    float v = w[idx] * f[q];
    w[idx] = v;
    ws += v;
  }
  #pragma unroll
  for (int off = 32; off >= 1; off >>= 1) ws += __shfl_xor(ws, off);
  if (lane == 0) rws[wv] = ws;
  __syncthreads();
  if (t == 0) W0[b * Hc + h] = rws[0] + rws[1] + rws[2] + rws[3];
}

// ---- select core: wave-shfl reductions, 3 barriers total ----
__device__ __forceinline__ void select_core(const float* __restrict__ ub,
                                            const int* histsh, int nhist, int t,
                                            int& gidx_out, float& lse_out, float& ent_out) {
  __shared__ float rf[4];
  __shared__ int ri[4];
  __shared__ float rs[4];
  __shared__ float re[4];
  int lane = t & 63, wv = t >> 6;
  float uval[8];
  float lmax = -3.0e38f;
  int lidx = 0;
  #pragma unroll
  for (int q = 0; q < 8; ++q) {
    int n = t + q * 256;
    float v = ub[n];
    for (int tt = 0; tt < nhist; ++tt)
      if (n == histsh[tt]) v = kNeg;
    uval[q] = v;
    if (v > lmax) { lmax = v; lidx = n; }   // strict > keeps lowest n
  }
  #pragma unroll
  for (int off = 32; off >= 1; off >>= 1) {
    float o = __shfl_xor(lmax, off);
    int oi = __shfl_xor(lidx, off);
    if (o > lmax || (o == lmax && oi < lidx)) { lmax = o; lidx = oi; }
  }
  if (lane == 0) { rf[wv] = lmax; ri[wv] = lidx; }
  __syncthreads();
  float mu = rf[0];
  int gidx = ri[0];
  #pragma unroll
  for (int k = 1; k < 4; ++k) {
    float o = rf[k]; int oi = ri[k];
    if (o > mu || (o == mu && oi < gidx)) { mu = o; gidx = oi; }
  }
  float ssum = 0.f;
  #pragma unroll
  for (int q = 0; q < 8; ++q) ssum += expf(uval[q] - mu);
  #pragma unroll
  for (int off = 32; off >= 1; off >>= 1) ssum += __shfl_xor(ssum, off);
  if (lane == 0) rs[wv] = ssum;
  __syncthreads();
  float Z = rs[0] + rs[1] + rs[2] + rs[3];
  float lse = mu + logf(Z);
  float ent = 0.f;
  #pragma unroll
  for (int q = 0; q < 8; ++q) {
    float logp = uval[q] - lse;
    float p = expf(logp);
    if (p > 0.f) ent -= p * logp;
  }
  #pragma unroll
  for (int off = 32; off >= 1; off >>= 1) ent += __shfl_xor(ent, off);
  if (lane == 0) re[wv] = ent;
  __syncthreads();
  ent_out = re[0] + re[1] + re[2] + re[3];
  gidx_out = gidx;
  lse_out = lse;
}

// ---- fused select(t-1) + chain(t): block per (b,h), select redundant ----
__global__ __launch_bounds__(256) void k_selchain(const float* __restrict__ u,
                                                  int* __restrict__ hist,
                                                  float* __restrict__ out,
                                                  const float* __restrict__ Sacc,
                                                  const float* __restrict__ W0,
                                                  const float* __restrict__ w,
                                                  const float* __restrict__ enc,
                                                  const float* __restrict__ BT,
                                                  float* __restrict__ rpart, int tstep) {
  int b = blockIdx.x >> 3, h = blockIdx.x & 7, t = threadIdx.x;
  __shared__ int histsh[16];
  __shared__ float sh[Dc];
  if (t < 16) histsh[t] = (t < tstep - 1) ? hist[b * 16 + t] : -1;
  __syncthreads();

  if (tstep > 0) {
    int sel_t = tstep - 1;
    int gidx; float lse, ent;
    select_core(u + (size_t)b * Nc, histsh, sel_t, t, gidx, lse, ent);
    if (h == 0 && t == 0) {
      float pi = expf(u[(size_t)b * Nc + gidx] - lse);
      out[b * Sc + sel_t] = (float)gidx;
      out[Bc * Sc + b * Sc + sel_t] = pi;
      if (sel_t == 0) out[2 * Bc * Sc + b] = ent;
      else out[2 * Bc * Sc + b] += ent;
      hist[b * 16 + sel_t] = gidx;
    }
    if (t == 0) histsh[sel_t] = gidx;
    __syncthreads();
  }

  // chain for own head
  float se = Sacc[((size_t)b * Hc + h) * Dc + t];
  float Wh = W0[b * Hc + h];
  for (int tt = 0; tt < tstep; ++tt) {
    int j = histsh[tt];
    float wv = w[((size_t)b * Hc + h) * Nc + j];
    se -= wv * enc[((size_t)b * Nc + j) * Dc + t];
    Wh -= wv;
  }
  sh[t] = se / Wh;
  __syncthreads();
  const float* bt = BT + (size_t)h * Dc * Dc + t;
  float a0 = 0.f, a1 = 0.f, a2 = 0.f, a3 = 0.f;
  #pragma unroll 4
  for (int e = 0; e < Dc; e += 4) {
    a0 += bt[(size_t)e * Dc] * sh[e];
    a1 += bt[(size_t)(e + 1) * Dc] * sh[e + 1];
    a2 += bt[(size_t)(e + 2) * Dc] * sh[e + 2];
    a3 += bt[(size_t)(e + 3) * Dc] * sh[e + 3];
  }
  rpart[((size_t)b * Hc + h) * Dc + t] = (a0 + a1) + (a2 + a3);
}

// ---- u scores: 4 threads per row, 2048 blocks ----
__global__ __launch_bounds__(256) void k_uscore(const float* __restrict__ enc,
                                                const float* __restrict__ rpart,
                                                const float* __restrict__ cvec,
                                                float* __restrict__ u) {
  int b = blockIdx.x >> 5, ng = blockIdx.x & 31, t = threadIdx.x;
  __shared__ __align__(16) float rsm[Dc];
  {
    float vsum = cvec[t];
    #pragma unroll
    for (int h = 0; h < Hc; ++h) vsum += rpart[((size_t)b * Hc + h) * Dc + t];
    rsm[t] = vsum;
  }
  __syncthreads();
  int row = t >> 2, q = t & 3;
  int n = ng * 64 + row;
  const float4* rowp = reinterpret_cast<const float4*>(enc + ((size_t)b * Nc + n) * Dc);
  const float4* r4 = reinterpret_cast<const float4*>(rsm);
  float acc = 0.f;
  #pragma unroll
  for (int i = 0; i < 16; ++i) {
    int d4 = i * 4 + q;
    const float4 e = rowp[d4];
    const float4 rr = r4[d4];
    acc += e.x * rr.x + e.y * rr.y + e.z * rr.z + e.w * rr.w;
  }
  acc += __shfl_xor(acc, 1);
  acc += __shfl_xor(acc, 2);
  if (q == 0) u[(size_t)b * Nc + n] = kClip * tanhf(kScale2 * acc);
}

// ---- final select (step Sc-1) ----
__global__ __launch_bounds__(256) void k_selfinal(const float* __restrict__ u,
                                                  const int* __restrict__ hist,
                                                  float* __restrict__ out) {
  int b = blockIdx.x, t = threadIdx.x;
  __shared__ int histsh[16];
  if (t < 16) histsh[t] = (t < Sc - 1) ? hist[b * 16 + t] : -1;
  __syncthreads();
  int gidx; float lse, ent;
  select_core(u + (size_t)b * Nc, histsh, Sc - 1, t, gidx, lse, ent);
  if (t == 0) {
    float pi = expf(u[(size_t)b * Nc + gidx] - lse);
    out[b * Sc + (Sc - 1)] = (float)gidx;
    out[Bc * Sc + b * Sc + (Sc - 1)] = pi;
    out[2 * Bc * Sc + b] += ent;
  }
}

extern "C" void kernel_launch(void* const* d_in, const int* in_sizes, int n_in,
                              void* d_out, int out_size, void* d_ws, size_t ws_size,
                              hipStream_t stream) {
  (void)in_sizes; (void)n_in; (void)out_size; (void)ws_size;
  const float* enc  = (const float*)d_in[0];
  const float* in_w = (const float*)d_in[1];
  const float* in_b = (const float*)d_in[2];
  const float* ow   = (const float*)d_in[3];
  const float* ob   = (const float*)d_in[4];
  const float* swq  = (const float*)d_in[5];
  const float* swk  = (const float*)d_in[6];
  float* out = (float*)d_out;

  float* ws = (float*)d_ws;
  size_t off = 0;
  auto alloc = [&](size_t n) { float* p = ws + off; off += n; return p; };
  float* hpart = alloc((size_t)Bc * 8 * Dc);
  float* g     = alloc((size_t)Bc * Hc * Dc);
  float* c     = alloc((size_t)Bc * Hc);
  float* w     = alloc((size_t)Bc * Hc * Nc);
  float* W0    = alloc((size_t)Bc * Hc);
  float* Spart = alloc((size_t)Bc * 8 * Hc * Dc);
  float* mrowc = alloc((size_t)Bc * 8 * Hc);
  float* Sacc  = alloc((size_t)Bc * Hc * Dc);
  float* M1    = alloc((size_t)Dc * Dc);
  float* m1b   = alloc(Dc);
  float* Aout  = alloc((size_t)Dc * Dc);
  float* cvec  = alloc(Dc);
  float* BT    = alloc((size_t)Hc * Dc * Dc);
  float* rpart = alloc((size_t)Bc * Hc * Dc);
  float* u     = alloc((size_t)Bc * Nc);
  int* hist    = (int*)alloc((size_t)Bc * 16);

  k_hmean_part<<<Bc * 8, 256, 0, stream>>>(enc, hpart);
  k_qgc<<<Bc, 256, 0, stream>>>(hpart, in_w, in_b, g, c);
  k_A1<<<Dc, 256, 0, stream>>>(swq, ow, ob, M1, m1b);
  k_A2<<<Dc, 256, 0, stream>>>(swk, M1, m1b, in_b, Aout, cvec);
  k_A3<<<Hc * 8, 256, 0, stream>>>(Aout, in_w, BT);
  k_scoreS0<<<Bc * 8, 256, 0, stream>>>(enc, g, c, w, Spart, mrowc);
  k_S0red<<<Bc * Hc, 256, 0, stream>>>(Spart, mrowc, w, Sacc, W0);

  for (int t = 0; t < Sc; ++t) {
    k_selchain<<<Bc * Hc, 256, 0, stream>>>(u, hist, out, Sacc, W0, w, enc, BT, rpart, t);
    k_uscore<<<Bc * 32, 256, 0, stream>>>(enc, rpart, cvec, u);
  }
  k_selfinal<<<Bc, 256, 0, stream>>>(u, hist, out);
}